// Round 6
// baseline (15224.074 us; speedup 1.0000x reference)
//
#include <hip/hip_runtime.h>
#include <cstddef>
#include <cstdint>

// ---------------------------------------------------------------------------
// GRU seq2seq via MFMA, 3-term bf16 split. TILE-OWNERSHIP edition:
// each wave owns whole C-tiles over full K (no cross-wave K-reduction),
// weights register-stationary at exactly 25 frag-pairs (200 VGPR) per wave.
// 32 clusters x 16 samples; 8 WGs/cluster (32 units each); WG = 8 waves.
// Window1: p1 tiles + p2 h-parts + proj (operands A=h1_prev, B=h0_prev, X).
// Window2 (after h0_new staged): p2 i-parts. 8 syncs + 2 L2 barriers/step.
// LDS acts chunk-XOR swizzled -> conflict-free ds_read_b128.
// ---------------------------------------------------------------------------

typedef __attribute__((ext_vector_type(8))) short short8v;
typedef __attribute__((ext_vector_type(4))) float float4v;

static const size_t OFF_H0A = 0;                    // 512*256
static const size_t OFF_H1A = 131072;
static const size_t OFF_H0B = 262144;
static const size_t OFF_H1B = 393216;
static const size_t OFF_WF  = 524288;               // 768*256
static const size_t OFF_BF  = OFF_WF + 196608;      // 768 (pad 1024)
static const size_t OFF_CTR = OFF_BF + 1024;        // 32*64 uints

#define SIGF(x) (1.0f / (1.0f + __expf(-(x))))
#define MFMA16 __builtin_amdgcn_mfma_f32_16x16x32_bf16
#define MM3(C, WH, WL, BH, BL) \
    C = MFMA16(WH, BH, C, 0, 0, 0); \
    C = MFMA16(WH, BL, C, 0, 0, 0); \
    C = MFMA16(WL, BH, C, 0, 0, 0);

__device__ __forceinline__ float agent_ld(const float* p) {
    return __hip_atomic_load(p, __ATOMIC_RELAXED, __HIP_MEMORY_SCOPE_AGENT);
}
__device__ __forceinline__ void agent_st(float* p, float v) {
    __hip_atomic_store(p, v, __ATOMIC_RELAXED, __HIP_MEMORY_SCOPE_AGENT);
}
__device__ __forceinline__ unsigned short f2bf(float x) {
    unsigned u = __float_as_uint(x);
    return (unsigned short)((u + 0x7FFFu + ((u >> 16) & 1u)) >> 16);
}
__device__ __forceinline__ float bf2f(unsigned short h) {
    return __uint_as_float(((unsigned)h) << 16);
}

// Wf = dec_Wih0 @ outW ; bf = dec_Wih0 @ out_b + dec_bih0
__global__ void fuse_wb(const float* __restrict__ Wih0, const float* __restrict__ oW,
                        const float* __restrict__ ob, const float* __restrict__ bih0,
                        float* __restrict__ Wf, float* __restrict__ bf) {
    int idx = blockIdx.x * 256 + threadIdx.x;
    int r = idx >> 8, h = idx & 255;
    const float* wr = Wih0 + (size_t)r * 128;
    float a = 0.f;
    for (int k = 0; k < 128; ++k) a = fmaf(wr[k], oW[(size_t)k * 256 + h], a);
    Wf[idx] = a;
    if (h == 0) {
        float b = 0.f;
        for (int k = 0; k < 128; ++k) b = fmaf(wr[k], ob[k], b);
        bf[r] = b + bih0[r];
    }
}

__global__ __launch_bounds__(512, 2) void behav_main(
    const float* __restrict__ pose,
    const float* __restrict__ eW0i, const float* __restrict__ eW0h,
    const float* __restrict__ eb0i, const float* __restrict__ eb0h,
    const float* __restrict__ eW1i, const float* __restrict__ eW1h,
    const float* __restrict__ eb1i, const float* __restrict__ eb1h,
    const float* __restrict__ dW0i, const float* __restrict__ dW0h,
    const float* __restrict__ db0i, const float* __restrict__ db0h,
    const float* __restrict__ dW1i, const float* __restrict__ dW1h,
    const float* __restrict__ db1i, const float* __restrict__ db1h,
    const float* __restrict__ oW, const float* __restrict__ ob,
    float* __restrict__ out,
    float* h0a, float* h0b, float* h1a, float* h1b,
    const float* __restrict__ Wf, const float* __restrict__ bf,
    unsigned* ctrs)
{
    // SLOT A: h1_prev. SLOT B: h0. Chunk-XOR swizzled (16B chunks).
    __shared__ short Ah[16][256], Al[16][256], Bh[16][256], Bl[16][256];  // 32KB
    __shared__ float4v G[24][64];                                         // 24KB
    // G slots: W1 dump: 0-3 p1.rz | 4-7 p1.n | 8-11 p2.rh | 12-15 p2.nhq
    //          | 16-23 proj partials (16 = reduced).
    // W2 dump (reuses dead p1): 0-3 p2.ri | 4-7 p2.niq.

    const int tid = threadIdx.x;
    const int lane = tid & 63;
    const int w = tid >> 6;
    const int q = w & 3;
    const int bid = blockIdx.x;
    const int xcd = bid & 7;
    const int inner = bid >> 3;
    const int uwg = inner & 7;
    const int c = ((inner >> 3) << 3) | xcd;    // XCD-pinned cluster
    const int s0 = c << 4, j0 = uwg << 5;
    unsigned* ctr = ctrs + (c << 6);
    unsigned epoch = 0;
    float* Gf = (float*)&G[0][0];

    float* h0buf[2] = { h0a, h0b };
    float* h1buf[2] = { h1a, h1b };
    int pp = 0;

    const size_t hoff = (size_t)(s0 + (tid >> 5)) * 256 + j0 + (tid & 31);
    const float4v FZ = {0.f, 0.f, 0.f, 0.f};
    const float obv = ((tid & 31) < 16) ? ob[(uwg << 4) + (tid & 31)] : 0.f;

    auto cbar = [&]() {
        __syncthreads();
        ++epoch;
        if (tid == 0) {
            __hip_atomic_fetch_add(ctr, 1u, __ATOMIC_RELAXED, __HIP_MEMORY_SCOPE_AGENT);
            unsigned tgt = epoch * 8u;
            while (__hip_atomic_load(ctr, __ATOMIC_RELAXED, __HIP_MEMORY_SCOPE_AGENT) < tgt)
                __builtin_amdgcn_s_sleep(1);
        }
        __syncthreads();
    };

    auto cvt8 = [&](const float* p, short8v& hv, short8v& lv) {
        float4 a = *(const float4*)p;
        float4 b = *(const float4*)(p + 4);
        float vv[8] = {a.x, a.y, a.z, a.w, b.x, b.y, b.z, b.w};
        #pragma unroll
        for (int i = 0; i < 8; ++i) {
            unsigned short h = f2bf(vv[i]);
            hv[i] = (short)h;
            lv[i] = (short)f2bf(vv[i] - bf2f(h));
        }
    };
    // A-frag: lane holds W[row0+(lane&15)][col0+(lane>>4)*8 ..+7]
    auto ldfrag = [&](const float* M, int ldm, int row0, int col0, short8v& hv, short8v& lv) {
        const float* p = M + (size_t)(row0 + (lane & 15)) * ldm + col0 + ((lane >> 4) << 3);
        cvt8(p, hv, lv);
    };
    // B-frag from swizzled LDS: logical chunk (kloc*4+o) at phys ^ (s&7)
    auto rdS = [&](const short (*arr)[256], int kloc) -> short8v {
        int s = lane & 15, o = lane >> 4;
        int phys = ((kloc << 2) + o) ^ (s & 7);
        return *(const short8v*)&arr[s][phys << 3];
    };
    auto rdX = [&](int t, int loc, short8v& bh, short8v& bl) {
        const float* p = pose + (size_t)(s0 + (lane & 15)) * 8192 + (size_t)t * 128
                         + (loc << 5) + ((lane >> 4) << 3);
        cvt8(p, bh, bl);
    };
    auto stage = [&](short (*ha)[256], short (*la)[256], const float* src) {
        int s = tid >> 5, cc = tid & 31;
        const float* p = src + (size_t)(s0 + s) * 256 + (cc << 3);
        short8v hv, lv;
        #pragma unroll
        for (int i = 0; i < 8; ++i) {
            float x = agent_ld(p + i);
            unsigned short h = f2bf(x);
            hv[i] = (short)h;
            lv[i] = (short)f2bf(x - bf2f(h));
        }
        int phys = cc ^ (s & 7);
        *(short8v*)&ha[s][phys << 3] = hv;
        *(short8v*)&la[s][phys << 3] = lv;
    };
    auto gread = [&](int slot, int r16, int s) -> float {
        return Gf[(slot << 8) + ((s + ((r16 >> 2) << 4)) << 2) + (r16 & 3)];
    };

    // ------------- register-stationary weights (25 frag-pairs/wave) -------------
    // role A (w<4):  WrzH[0..7]=p1.rz i-part, [8..15]=p1.rz h-part;
    //                WnH[0..3]=p2.nh quarter (A-src), [4..7]=p2.ni quarter (B-src)
    // role B (w>=4): WrzH[0..7]=p2.rz h-part (A-src), [8..15]=p2.rz i-part (B-src);
    //                WnH[0..7]=p1.n (q<2: ni i-part; q>=2: nh h-part)
    short8v WrzH[16], WrzL[16], WnH[8], WnL[8], PJH, PJL;
    float b0r, b0z, b0ni, b0nh, b1r, b1z, b1ni, b1nh;

    auto load_era = [&](const float* W0i, bool x128, const float* W0h,
                        const float* W1i, const float* W1h) {
        const int rzrow = ((q >> 1) ? 256 : 0) + j0 + ((q & 1) << 4);
        if (w < 4) {
            if (x128) {
                #pragma unroll
                for (int i = 0; i < 4; ++i) ldfrag(W0i, 128, rzrow, i << 5, WrzH[i], WrzL[i]);
            } else {
                #pragma unroll
                for (int i = 0; i < 8; ++i) ldfrag(W0i, 256, rzrow, i << 5, WrzH[i], WrzL[i]);
            }
            #pragma unroll
            for (int i = 0; i < 8; ++i) ldfrag(W0h, 256, rzrow, i << 5, WrzH[8 + i], WrzL[8 + i]);
            const int nrow = 512 + j0 + ((q >> 1) << 4);
            #pragma unroll
            for (int i = 0; i < 4; ++i) {
                int kl = ((q & 1) << 2) + i;
                ldfrag(W1h, 256, nrow, kl << 5, WnH[i], WnL[i]);
                ldfrag(W1i, 256, nrow, kl << 5, WnH[4 + i], WnL[4 + i]);
            }
        } else {
            #pragma unroll
            for (int i = 0; i < 8; ++i) {
                ldfrag(W1h, 256, rzrow, i << 5, WrzH[i], WrzL[i]);
                ldfrag(W1i, 256, rzrow, i << 5, WrzH[8 + i], WrzL[8 + i]);
            }
            if (q < 2) {
                const int nrow = 512 + j0 + (q << 4);
                if (x128) {
                    #pragma unroll
                    for (int i = 0; i < 4; ++i) ldfrag(W0i, 128, nrow, i << 5, WnH[i], WnL[i]);
                } else {
                    #pragma unroll
                    for (int i = 0; i < 8; ++i) ldfrag(W0i, 256, nrow, i << 5, WnH[i], WnL[i]);
                }
            } else {
                const int nrow = 512 + j0 + ((q - 2) << 4);
                #pragma unroll
                for (int i = 0; i < 8; ++i) ldfrag(W0h, 256, nrow, i << 5, WnH[i], WnL[i]);
            }
        }
    };
    auto ldb0 = [&](const float* bi, const float* bhh) {
        int jj = j0 + (tid & 31);
        b0r = bi[jj] + bhh[jj]; b0z = bi[256 + jj] + bhh[256 + jj];
        b0ni = bi[512 + jj]; b0nh = bhh[512 + jj];
    };
    auto ldb1 = [&](const float* bi, const float* bhh) {
        int jj = j0 + (tid & 31);
        b1r = bi[jj] + bhh[jj]; b1z = bi[256 + jj] + bhh[256 + jj];
        b1ni = bi[512 + jj]; b1nh = bhh[512 + jj];
    };

    // ------------- windows -------------
    auto W1_fn = [&](int t, bool xs, bool pj) {
        if (w < 4) {
            float4v Ca[2] = {FZ, FZ};
            if (xs) {
                #pragma unroll
                for (int i = 0; i < 4; ++i) {
                    short8v bh, bl; rdX(t, i, bh, bl);
                    MM3(Ca[i & 1], WrzH[i], WrzL[i], bh, bl);
                }
            } else {
                #pragma unroll
                for (int i = 0; i < 8; ++i) {
                    short8v bh = rdS(Ah, i), bl = rdS(Al, i);
                    MM3(Ca[i & 1], WrzH[i], WrzL[i], bh, bl);
                }
            }
            #pragma unroll
            for (int i = 0; i < 8; ++i) {
                short8v bh = rdS(Bh, i), bl = rdS(Bl, i);
                MM3(Ca[i & 1], WrzH[8 + i], WrzL[8 + i], bh, bl);
            }
            G[q][lane] = Ca[0] + Ca[1];
            float4v Cn = FZ;
            #pragma unroll
            for (int i = 0; i < 4; ++i) {
                int kl = ((q & 1) << 2) + i;
                short8v bh = rdS(Ah, kl), bl = rdS(Al, kl);
                MM3(Cn, WnH[i], WnL[i], bh, bl);
            }
            G[12 + q][lane] = Cn;
        } else {
            float4v Cn = FZ;
            if (q < 2) {
                if (xs) {
                    #pragma unroll
                    for (int i = 0; i < 4; ++i) {
                        short8v bh, bl; rdX(t, i, bh, bl);
                        MM3(Cn, WnH[i], WnL[i], bh, bl);
                    }
                } else {
                    #pragma unroll
                    for (int i = 0; i < 8; ++i) {
                        short8v bh = rdS(Ah, i), bl = rdS(Al, i);
                        MM3(Cn, WnH[i], WnL[i], bh, bl);
                    }
                }
            } else {
                #pragma unroll
                for (int i = 0; i < 8; ++i) {
                    short8v bh = rdS(Bh, i), bl = rdS(Bl, i);
                    MM3(Cn, WnH[i], WnL[i], bh, bl);
                }
            }
            G[4 + q][lane] = Cn;
            float4v Ch[2] = {FZ, FZ};
            #pragma unroll
            for (int i = 0; i < 8; ++i) {
                short8v bh = rdS(Ah, i), bl = rdS(Al, i);
                MM3(Ch[i & 1], WrzH[i], WrzL[i], bh, bl);
            }
            G[8 + q][lane] = Ch[0] + Ch[1];
        }
        if (pj) {
            float4v Cp = FZ;
            short8v bh = rdS(Ah, w), bl = rdS(Al, w);
            MM3(Cp, PJH, PJL, bh, bl);
            G[16 + w][lane] = Cp;
        }
    };
    auto W2_fn = [&]() {
        if (w < 4) {
            float4v Cn = FZ;
            #pragma unroll
            for (int i = 0; i < 4; ++i) {
                int kl = ((q & 1) << 2) + i;
                short8v bh = rdS(Bh, kl), bl = rdS(Bl, kl);
                MM3(Cn, WnH[4 + i], WnL[4 + i], bh, bl);
            }
            G[4 + q][lane] = Cn;
        } else {
            float4v Ci[2] = {FZ, FZ};
            #pragma unroll
            for (int i = 0; i < 8; ++i) {
                short8v bh = rdS(Bh, i), bl = rdS(Bl, i);
                MM3(Ci[i & 1], WrzH[8 + i], WrzL[8 + i], bh, bl);
            }
            G[q][lane] = Ci[0] + Ci[1];
        }
    };
    auto epi1 = [&](float hp, float* pong) {
        int s = tid >> 5, ul = tid & 31;
        int t2 = ul >> 4, r16 = ul & 15;
        float r = SIGF(gread(t2, r16, s) + b0r);
        float z = SIGF(gread(2 + t2, r16, s) + b0z);
        float n = tanhf(gread(4 + t2, r16, s) + b0ni + r * (gread(6 + t2, r16, s) + b0nh));
        agent_st(pong + (size_t)(s0 + s) * 256 + j0 + ul, (1.f - z) * n + z * hp);
    };
    auto epi2 = [&](float hp, float* pong) {
        int s = tid >> 5, ul = tid & 31;
        int t2 = ul >> 4, r16 = ul & 15;
        float r = SIGF(gread(t2, r16, s) + gread(8 + t2, r16, s) + b1r);
        float z = SIGF(gread(2 + t2, r16, s) + gread(10 + t2, r16, s) + b1z);
        float ni = gread(4 + (t2 << 1), r16, s) + gread(5 + (t2 << 1), r16, s);
        float nh = gread(12 + (t2 << 1), r16, s) + gread(13 + (t2 << 1), r16, s);
        float n = tanhf(ni + b1ni + r * (nh + b1nh));
        agent_st(pong + (size_t)(s0 + s) * 256 + j0 + ul, (1.f - z) * n + z * hp);
    };
    auto red_pj = [&]() {
        if (tid < 64) {
            G[16][tid] = G[16][tid] + G[17][tid] + G[18][tid] + G[19][tid]
                       + G[20][tid] + G[21][tid] + G[22][tid] + G[23][tid];
        }
    };
    auto epi_proj = [&](int tq) {
        int s = tid >> 5, ul = tid & 31;
        if (ul < 16) {
            float v = gread(16, ul, s) + obv;
            out[(size_t)(s0 + s) * 65536 + (size_t)tq * 128 + (uwg << 4) + ul] = v;
        }
    };

    auto step = [&](int t, bool xs, bool pj) {
        float hp0 = agent_ld(h0buf[pp] + hoff);
        float hp1 = agent_ld(h1buf[pp] + hoff);
        W1_fn(t, xs, pj);
        __syncthreads();                    // sync1: W1 dumps visible
        if (pj) red_pj();
        epi1(hp0, h0buf[pp ^ 1]);
        cbar();                             // cbar1: h0_new global-visible
        stage(Bh, Bl, h0buf[pp ^ 1]);
        if (pj) epi_proj(t - 1);
        __syncthreads();                    // sync2: slot B ready
        W2_fn();
        __syncthreads();                    // sync3: W2 dumps visible
        epi2(hp1, h1buf[pp ^ 1]);
        cbar();                             // cbar2: h1_new global-visible
        stage(Ah, Al, h1buf[pp ^ 1]);
        __syncthreads();                    // sync4: slot A ready
        pp ^= 1;
    };

    // ------------- init -------------
    {
        short8v zz = {0, 0, 0, 0, 0, 0, 0, 0};
        int s = tid >> 5, cc = tid & 31;
        *(short8v*)&Ah[s][cc << 3] = zz;
        *(short8v*)&Al[s][cc << 3] = zz;
        *(short8v*)&Bh[s][cc << 3] = zz;
        *(short8v*)&Bl[s][cc << 3] = zz;
    }
    ldfrag(oW, 256, uwg << 4, w << 5, PJH, PJL);
    __syncthreads();

    // ===================== ENCODER =====================
    load_era(eW0i, true, eW0h, eW1i, eW1h);
    ldb0(eb0i, eb0h); ldb1(eb1i, eb1h);
    for (int t = 0; t < 64; ++t) step(t, true, false);

    // ===================== DECODER: teacher =====================
    load_era(dW0i, true, dW0h, dW1i, dW1h);
    ldb0(db0i, db0h); ldb1(db1i, db1h);
    step(0, true, false);
    for (int t = 1; t < 64; ++t) step(t, true, true);

    // ===================== DECODER: autoregressive =====================
    load_era(Wf, false, dW0h, dW1i, dW1h);
    {
        int jj = j0 + (tid & 31);
        b0r = bf[jj] + db0h[jj];
        b0z = bf[256 + jj] + db0h[256 + jj];
        b0ni = bf[512 + jj];
        b0nh = db0h[512 + jj];
    }
    for (int t = 64; t < 512; ++t) step(t, false, true);

    // ===================== tail: out[511] = proj(h1_511) =====================
    {
        float4v Cp = FZ;
        short8v bh = rdS(Ah, w), bl = rdS(Al, w);
        MM3(Cp, PJH, PJL, bh, bl);
        G[16 + w][lane] = Cp;
        __syncthreads();
        red_pj();
        __syncthreads();
        epi_proj(511);
    }
}

extern "C" void kernel_launch(void* const* d_in, const int* in_sizes, int n_in,
                              void* d_out, int out_size, void* d_ws, size_t ws_size,
                              hipStream_t stream) {
    (void)in_sizes; (void)n_in; (void)out_size; (void)ws_size;

    const float* pose = (const float*)d_in[0];
    const float* eW0i = (const float*)d_in[1];
    const float* eW0h = (const float*)d_in[2];
    const float* eb0i = (const float*)d_in[3];
    const float* eb0h = (const float*)d_in[4];
    const float* eW1i = (const float*)d_in[5];
    const float* eW1h = (const float*)d_in[6];
    const float* eb1i = (const float*)d_in[7];
    const float* eb1h = (const float*)d_in[8];
    const float* dW0i = (const float*)d_in[9];
    const float* dW0h = (const float*)d_in[10];
    const float* db0i = (const float*)d_in[11];
    const float* db0h = (const float*)d_in[12];
    const float* dW1i = (const float*)d_in[13];
    const float* dW1h = (const float*)d_in[14];
    const float* db1i = (const float*)d_in[15];
    const float* db1h = (const float*)d_in[16];
    const float* oW   = (const float*)d_in[17];
    const float* ob   = (const float*)d_in[18];

    float* ws = (float*)d_ws;
    float* h0a = ws + OFF_H0A;
    float* h0b = ws + OFF_H0B;
    float* h1a = ws + OFF_H1A;
    float* h1b = ws + OFF_H1B;
    float* Wf  = ws + OFF_WF;
    float* bf  = ws + OFF_BF;
    unsigned* ctrs = (unsigned*)(ws + OFF_CTR);
    float* outf = (float*)d_out;

    hipMemsetAsync(d_ws, 0, 262144 * sizeof(float), stream);   // ping h0+h1 = 0
    hipMemsetAsync((void*)ctrs, 0, 32 * 64 * sizeof(unsigned), stream);

    fuse_wb<<<dim3(768), dim3(256), 0, stream>>>(dW0i, oW, ob, db0i, Wf, bf);

    void* kargs[] = {
        (void*)&pose,
        (void*)&eW0i, (void*)&eW0h, (void*)&eb0i, (void*)&eb0h,
        (void*)&eW1i, (void*)&eW1h, (void*)&eb1i, (void*)&eb1h,
        (void*)&dW0i, (void*)&dW0h, (void*)&db0i, (void*)&db0h,
        (void*)&dW1i, (void*)&dW1h, (void*)&db1i, (void*)&db1h,
        (void*)&oW, (void*)&ob,
        (void*)&outf,
        (void*)&h0a, (void*)&h0b, (void*)&h1a, (void*)&h1b,
        (void*)&Wf, (void*)&bf,
        (void*)&ctrs
    };
    hipLaunchCooperativeKernel((const void*)behav_main, dim3(256), dim3(512),
                               kargs, 0, stream);
}

// Round 7
// 5332.943 us; speedup vs baseline: 2.8547x; 2.8547x over previous
//
#include <hip/hip_runtime.h>
#include <cstddef>
#include <cstdint>

// ---------------------------------------------------------------------------
// GRU seq2seq via MFMA. fp16 weights (single copy, systematic 2^-11) x
// fp16 hi/lo-split activations (2 MFMAs per chunk).
// 32 clusters x 16 samples; 8 WGs/cluster (32 units each); WG = 8 waves.
// Tile-ownership, balanced: W1 = p1 tiles + p2 h-halves + proj (ops A,B,X);
// W2 = p2 i-parts (op h0_new). Weights register-stationary: <=28 frags
// (112 VGPR) per wave via explicit WA/WB/WC overlay.
// amdgpu_waves_per_eu(2,2) pins the VGPR budget at 256 (r5/r6 evidence:
// launch_bounds(512,2) capped at 128 -> mass spill).
// ---------------------------------------------------------------------------

typedef __attribute__((ext_vector_type(8))) _Float16 half8v;
typedef __attribute__((ext_vector_type(4))) float float4v;

static const size_t OFF_H0A = 0;                    // 512*256
static const size_t OFF_H1A = 131072;
static const size_t OFF_H0B = 262144;
static const size_t OFF_H1B = 393216;
static const size_t OFF_WF  = 524288;               // 768*256
static const size_t OFF_BF  = OFF_WF + 196608;      // 768 (pad 1024)
static const size_t OFF_CTR = OFF_BF + 1024;        // 32*64 uints

#define SIGF(x) (1.0f / (1.0f + __expf(-(x))))
#define MFMA16F __builtin_amdgcn_mfma_f32_16x16x32_f16
#define MM2(C, W, BH, BL) \
    C = MFMA16F(W, BH, C, 0, 0, 0); \
    C = MFMA16F(W, BL, C, 0, 0, 0);

__device__ __forceinline__ float agent_ld(const float* p) {
    return __hip_atomic_load(p, __ATOMIC_RELAXED, __HIP_MEMORY_SCOPE_AGENT);
}
__device__ __forceinline__ void agent_st(float* p, float v) {
    __hip_atomic_store(p, v, __ATOMIC_RELAXED, __HIP_MEMORY_SCOPE_AGENT);
}

// Wf = dec_Wih0 @ outW ; bf = dec_Wih0 @ out_b + dec_bih0
__global__ void fuse_wb(const float* __restrict__ Wih0, const float* __restrict__ oW,
                        const float* __restrict__ ob, const float* __restrict__ bih0,
                        float* __restrict__ Wf, float* __restrict__ bf) {
    int idx = blockIdx.x * 256 + threadIdx.x;
    int r = idx >> 8, h = idx & 255;
    const float* wr = Wih0 + (size_t)r * 128;
    float a = 0.f;
    for (int k = 0; k < 128; ++k) a = fmaf(wr[k], oW[(size_t)k * 256 + h], a);
    Wf[idx] = a;
    if (h == 0) {
        float b = 0.f;
        for (int k = 0; k < 128; ++k) b = fmaf(wr[k], ob[k], b);
        bf[r] = b + bih0[r];
    }
}

__global__ __attribute__((amdgpu_waves_per_eu(2, 2))) __launch_bounds__(512)
void behav_main(
    const float* __restrict__ pose,
    const float* __restrict__ eW0i, const float* __restrict__ eW0h,
    const float* __restrict__ eb0i, const float* __restrict__ eb0h,
    const float* __restrict__ eW1i, const float* __restrict__ eW1h,
    const float* __restrict__ eb1i, const float* __restrict__ eb1h,
    const float* __restrict__ dW0i, const float* __restrict__ dW0h,
    const float* __restrict__ db0i, const float* __restrict__ db0h,
    const float* __restrict__ dW1i, const float* __restrict__ dW1h,
    const float* __restrict__ db1i, const float* __restrict__ db1h,
    const float* __restrict__ oW, const float* __restrict__ ob,
    float* __restrict__ out,
    float* h0a, float* h0b, float* h1a, float* h1b,
    const float* __restrict__ Wf, const float* __restrict__ bf,
    unsigned* ctrs)
{
    // SLOT A: h1_prev. SLOT B: h0. fp16 hi/lo, chunk-XOR swizzled.
    __shared__ _Float16 Ah[16][256], Al[16][256], Bh[16][256], Bl[16][256]; // 32KB
    __shared__ float4v G[24][64];                                           // 24KB
    // G: W1: 0-5 p1 tiles [r0,r1,z0,z1,n0i,n1i] | 22,23 p1 n0h,n1h
    //        6-17 p2 h-halves [tile*2+khalf] | 18,19 proj halves
    //    W2 (reuse): 0-3 p2 i full tiles r0,r1,z0,z1 | 4,5 n0i halves | 20,21 n1i halves

    const int tid = threadIdx.x;
    const int lane = tid & 63;
    const int w = tid >> 6;
    const int bid = blockIdx.x;
    const int xcd = bid & 7;
    const int inner = bid >> 3;
    const int uwg = inner & 7;
    const int c = ((inner >> 3) << 3) | xcd;    // XCD-pinned cluster
    const int s0 = c << 4, j0 = uwg << 5;
    unsigned* ctr = ctrs + (c << 6);
    unsigned epoch = 0;
    float* Gf = (float*)&G[0][0];

    float* h0buf[2] = { h0a, h0b };
    float* h1buf[2] = { h1a, h1b };
    int pp = 0;

    const size_t hoff = (size_t)(s0 + (tid >> 5)) * 256 + j0 + (tid & 31);
    const float4v FZ = {0.f, 0.f, 0.f, 0.f};
    const float obv = ((tid & 31) < 16) ? ob[(uwg << 4) + (tid & 31)] : 0.f;

    auto cbar = [&]() {
        __syncthreads();
        ++epoch;
        if (tid == 0) {
            __hip_atomic_fetch_add(ctr, 1u, __ATOMIC_RELAXED, __HIP_MEMORY_SCOPE_AGENT);
            unsigned tgt = epoch * 8u;
            while (__hip_atomic_load(ctr, __ATOMIC_RELAXED, __HIP_MEMORY_SCOPE_AGENT) < tgt)
                __builtin_amdgcn_s_sleep(1);
        }
        __syncthreads();
    };

    // weight frag: lane holds W[row0+(lane&15)][col0+(lane>>4)*8 ..+7] as fp16
    auto ldfrag = [&](const float* M, int ldm, int row0, int col0, half8v& wv) {
        const float* p = M + (size_t)(row0 + (lane & 15)) * ldm + col0 + ((lane >> 4) << 3);
        float4 a = *(const float4*)p;
        float4 b = *(const float4*)(p + 4);
        float vv[8] = {a.x, a.y, a.z, a.w, b.x, b.y, b.z, b.w};
        #pragma unroll
        for (int i = 0; i < 8; ++i) wv[i] = (_Float16)vv[i];
    };
    // B-frag from swizzled LDS
    auto rdS = [&](const _Float16 (*arr)[256], int kloc) -> half8v {
        int s = lane & 15, o = lane >> 4;
        int phys = ((kloc << 2) + o) ^ (s & 7);
        return *(const half8v*)&arr[s][phys << 3];
    };
    auto rdX = [&](int t, int loc, half8v& bh, half8v& bl) {
        const float* p = pose + (size_t)(s0 + (lane & 15)) * 8192 + (size_t)t * 128
                         + (loc << 5) + ((lane >> 4) << 3);
        float4 a = *(const float4*)p;
        float4 b = *(const float4*)(p + 4);
        float vv[8] = {a.x, a.y, a.z, a.w, b.x, b.y, b.z, b.w};
        #pragma unroll
        for (int i = 0; i < 8; ++i) {
            _Float16 h = (_Float16)vv[i];
            bh[i] = h;
            bl[i] = (_Float16)(vv[i] - (float)h);
        }
    };
    auto stage = [&](_Float16 (*ha)[256], _Float16 (*la)[256], const float* src) {
        int s = tid >> 5, cc = tid & 31;
        const float* p = src + (size_t)(s0 + s) * 256 + (cc << 3);
        half8v hv, lv;
        #pragma unroll
        for (int i = 0; i < 8; ++i) {
            float x = agent_ld(p + i);
            _Float16 h = (_Float16)x;
            hv[i] = h;
            lv[i] = (_Float16)(x - (float)h);
        }
        int phys = cc ^ (s & 7);
        *(half8v*)&ha[s][phys << 3] = hv;
        *(half8v*)&la[s][phys << 3] = lv;
    };
    auto grd = [&](int slot, int r16, int s) -> float {
        return Gf[(slot << 8) + ((s + ((r16 >> 2) << 4)) << 2) + (r16 & 3)];
    };

    // ---- register-stationary weights: explicit overlay, <=28 frags/wave ----
    // w<6:  WA[0..7]=p1 i-side, WA[8..15]=p1 h-side; WC[0..3]=p2h half w;
    //       WB = W2 i-frags (w<4: 8; w=4,5: 4 for n-halves k0)
    // w>=6: WA[0..11]=3 p2h halves; WA[12..15]=proj; WB[0..3]=W2 n-half k1
    half8v WA[16], WB[8], WC[4];
    float b0r, b0z, b0ni, b0nh, b1r, b1z, b1ni, b1nh;

    auto load_era = [&](const float* W0i, bool x128, const float* W0h,
                        const float* W1i, const float* W1h) {
        if (w < 6) {
            const int rb1 = ((w >> 1) << 8) + j0 + ((w & 1) << 4);
            if (x128) {
                #pragma unroll
                for (int cc = 0; cc < 4; ++cc) ldfrag(W0i, 128, rb1, cc << 5, WA[cc]);
            } else {
                #pragma unroll
                for (int cc = 0; cc < 8; ++cc) ldfrag(W0i, 256, rb1, cc << 5, WA[cc]);
            }
            #pragma unroll
            for (int cc = 0; cc < 8; ++cc) ldfrag(W0h, 256, rb1, cc << 5, WA[8 + cc]);
            const int t2 = w >> 1;
            const int rb2 = ((t2 >> 1) << 8) + j0 + ((t2 & 1) << 4);
            const int kb = (w & 1) << 2;
            #pragma unroll
            for (int cc = 0; cc < 4; ++cc) ldfrag(W1h, 256, rb2, (kb + cc) << 5, WC[cc]);
            if (w < 4) {
                #pragma unroll
                for (int cc = 0; cc < 8; ++cc) ldfrag(W1i, 256, rb1, cc << 5, WB[cc]);
            } else {
                const int rb3 = 512 + j0 + ((w - 4) << 4);
                #pragma unroll
                for (int cc = 0; cc < 4; ++cc) ldfrag(W1i, 256, rb3, cc << 5, WB[cc]);
            }
        } else {
            #pragma unroll
            for (int j = 0; j < 3; ++j) {
                const int hh = 6 + (w - 6) * 3 + j;
                const int t2 = hh >> 1;
                const int rb2 = ((t2 >> 1) << 8) + j0 + ((t2 & 1) << 4);
                const int kb = (hh & 1) << 2;
                #pragma unroll
                for (int cc = 0; cc < 4; ++cc)
                    ldfrag(W1h, 256, rb2, (kb + cc) << 5, WA[4 * j + cc]);
            }
            #pragma unroll
            for (int cc = 0; cc < 4; ++cc)
                ldfrag(oW, 256, uwg << 4, (((w - 6) << 2) + cc) << 5, WA[12 + cc]);
            const int rb3 = 512 + j0 + ((w - 6) << 4);
            #pragma unroll
            for (int cc = 0; cc < 4; ++cc) ldfrag(W1i, 256, rb3, (4 + cc) << 5, WB[cc]);
        }
    };
    auto ldb0 = [&](const float* bi, const float* bhh) {
        int jj = j0 + (tid & 31);
        b0r = bi[jj] + bhh[jj]; b0z = bi[256 + jj] + bhh[256 + jj];
        b0ni = bi[512 + jj]; b0nh = bhh[512 + jj];
    };
    auto ldb1 = [&](const float* bi, const float* bhh) {
        int jj = j0 + (tid & 31);
        b1r = bi[jj] + bhh[jj]; b1z = bi[256 + jj] + bhh[256 + jj];
        b1ni = bi[512 + jj]; b1nh = bhh[512 + jj];
    };

    // ---- windows ----
    auto W1_fn = [&](int t, bool xs, bool pj) {
        if (w < 6) {
            float4v accI = FZ, accH = FZ;
            if (xs) {
                #pragma unroll
                for (int cc = 0; cc < 4; ++cc) {
                    half8v bh, bl; rdX(t, cc, bh, bl);
                    MM2(accI, WA[cc], bh, bl);
                }
            } else {
                #pragma unroll
                for (int cc = 0; cc < 8; ++cc) {
                    half8v bh = rdS(Ah, cc), bl = rdS(Al, cc);
                    MM2(accI, WA[cc], bh, bl);
                }
            }
            if (w >= 4) {
                #pragma unroll
                for (int cc = 0; cc < 8; ++cc) {
                    half8v bh = rdS(Bh, cc), bl = rdS(Bl, cc);
                    MM2(accH, WA[8 + cc], bh, bl);
                }
                G[w][lane] = accI;
                G[22 + (w - 4)][lane] = accH;
            } else {
                #pragma unroll
                for (int cc = 0; cc < 8; ++cc) {
                    half8v bh = rdS(Bh, cc), bl = rdS(Bl, cc);
                    MM2(accI, WA[8 + cc], bh, bl);
                }
                G[w][lane] = accI;
            }
            float4v accP = FZ;
            const int kb = (w & 1) << 2;
            #pragma unroll
            for (int cc = 0; cc < 4; ++cc) {
                half8v bh = rdS(Ah, kb + cc), bl = rdS(Al, kb + cc);
                MM2(accP, WC[cc], bh, bl);
            }
            G[6 + w][lane] = accP;
        } else {
            #pragma unroll
            for (int j = 0; j < 3; ++j) {
                const int hh = 6 + (w - 6) * 3 + j;
                const int kb = (hh & 1) << 2;
                float4v accP = FZ;
                #pragma unroll
                for (int cc = 0; cc < 4; ++cc) {
                    half8v bh = rdS(Ah, kb + cc), bl = rdS(Al, kb + cc);
                    MM2(accP, WA[4 * j + cc], bh, bl);
                }
                G[6 + hh][lane] = accP;
            }
            if (pj) {
                float4v accJ = FZ;
                const int cb = (w - 6) << 2;
                #pragma unroll
                for (int cc = 0; cc < 4; ++cc) {
                    half8v bh = rdS(Ah, cb + cc), bl = rdS(Al, cb + cc);
                    MM2(accJ, WA[12 + cc], bh, bl);
                }
                G[18 + (w - 6)][lane] = accJ;
            }
        }
    };
    auto W2_fn = [&]() {
        if (w < 4) {
            float4v acc = FZ;
            #pragma unroll
            for (int cc = 0; cc < 8; ++cc) {
                half8v bh = rdS(Bh, cc), bl = rdS(Bl, cc);
                MM2(acc, WB[cc], bh, bl);
            }
            G[w][lane] = acc;
        } else {
            float4v acc = FZ;
            const int kb = (w >= 6) ? 4 : 0;
            #pragma unroll
            for (int cc = 0; cc < 4; ++cc) {
                half8v bh = rdS(Bh, kb + cc), bl = rdS(Bl, kb + cc);
                MM2(acc, WB[cc], bh, bl);
            }
            const int sl = (w == 4) ? 4 : (w == 5) ? 20 : (w == 6) ? 5 : 21;
            G[sl][lane] = acc;
        }
    };
    auto epi1 = [&](float hp, float* pong) {
        int s = tid >> 5, ul = tid & 31, t2 = ul >> 4, r16 = ul & 15;
        float r = SIGF(grd(t2, r16, s) + b0r);
        float z = SIGF(grd(2 + t2, r16, s) + b0z);
        float n = tanhf(grd(4 + t2, r16, s) + b0ni + r * (grd(22 + t2, r16, s) + b0nh));
        agent_st(pong + (size_t)(s0 + s) * 256 + j0 + ul, (1.f - z) * n + z * hp);
    };
    auto epi2 = [&](float hp, float* pong) {
        int s = tid >> 5, ul = tid & 31, t2 = ul >> 4, r16 = ul & 15;
        float r = SIGF(grd(t2, r16, s) + grd(6 + (t2 << 1), r16, s)
                       + grd(7 + (t2 << 1), r16, s) + b1r);
        float z = SIGF(grd(2 + t2, r16, s) + grd(10 + (t2 << 1), r16, s)
                       + grd(11 + (t2 << 1), r16, s) + b1z);
        int nia = t2 ? 20 : 4, nib = t2 ? 21 : 5;
        float ni = grd(nia, r16, s) + grd(nib, r16, s);
        float nh = grd(14 + (t2 << 1), r16, s) + grd(15 + (t2 << 1), r16, s);
        float n = tanhf(ni + b1ni + r * (nh + b1nh));
        agent_st(pong + (size_t)(s0 + s) * 256 + j0 + ul, (1.f - z) * n + z * hp);
    };
    auto epi_proj = [&](int tq) {
        int s = tid >> 5, ul = tid & 31;
        if (ul < 16) {
            float v = grd(18, ul, s) + grd(19, ul, s) + obv;
            out[(size_t)(s0 + s) * 65536 + (size_t)tq * 128 + (uwg << 4) + ul] = v;
        }
    };

    auto step = [&](int t, bool xs, bool pj) {
        float hp0 = agent_ld(h0buf[pp] + hoff);
        float hp1 = agent_ld(h1buf[pp] + hoff);
        W1_fn(t, xs, pj);
        __syncthreads();                    // sync1: W1 dumps visible
        epi1(hp0, h0buf[pp ^ 1]);
        if (pj) epi_proj(t - 1);
        cbar();                             // cbar1: h0_new global-visible
        stage(Bh, Bl, h0buf[pp ^ 1]);
        __syncthreads();                    // sync2: slot B = h0_new ready
        W2_fn();
        __syncthreads();                    // sync3: W2 dumps visible
        epi2(hp1, h1buf[pp ^ 1]);
        cbar();                             // cbar2: h1_new global-visible
        stage(Ah, Al, h1buf[pp ^ 1]);
        __syncthreads();                    // sync4: slot A = h1_new ready
        pp ^= 1;
    };

    // ---- init ----
    {
        int s = tid >> 5, cc = tid & 31;
        half8v z;
        #pragma unroll
        for (int i = 0; i < 8; ++i) z[i] = (_Float16)0.f;
        *(half8v*)&Ah[s][cc << 3] = z;
        *(half8v*)&Al[s][cc << 3] = z;
        *(half8v*)&Bh[s][cc << 3] = z;
        *(half8v*)&Bl[s][cc << 3] = z;
    }
    __syncthreads();

    // ===================== ENCODER =====================
    load_era(eW0i, true, eW0h, eW1i, eW1h);
    ldb0(eb0i, eb0h); ldb1(eb1i, eb1h);
    for (int t = 0; t < 64; ++t) step(t, true, false);

    // ===================== DECODER: teacher =====================
    load_era(dW0i, true, dW0h, dW1i, dW1h);
    ldb0(db0i, db0h); ldb1(db1i, db1h);
    step(0, true, false);
    for (int t = 1; t < 64; ++t) step(t, true, true);

    // ===================== DECODER: autoregressive =====================
    if (w < 6) {
        const int rb1 = ((w >> 1) << 8) + j0 + ((w & 1) << 4);
        #pragma unroll
        for (int cc = 0; cc < 8; ++cc) ldfrag(Wf, 256, rb1, cc << 5, WA[cc]);
    }
    {
        int jj = j0 + (tid & 31);
        b0r = bf[jj] + db0h[jj];
        b0z = bf[256 + jj] + db0h[256 + jj];
        b0ni = bf[512 + jj];
        b0nh = db0h[512 + jj];
    }
    for (int t = 64; t < 512; ++t) step(t, false, true);

    // ===================== tail: out[511] = proj(h1_511) =====================
    if (w >= 6) {
        float4v accJ = FZ;
        const int cb = (w - 6) << 2;
        #pragma unroll
        for (int cc = 0; cc < 4; ++cc) {
            half8v bh = rdS(Ah, cb + cc), bl = rdS(Al, cb + cc);
            MM2(accJ, WA[12 + cc], bh, bl);
        }
        G[18 + (w - 6)][lane] = accJ;
    }
    __syncthreads();
    epi_proj(511);
}

extern "C" void kernel_launch(void* const* d_in, const int* in_sizes, int n_in,
                              void* d_out, int out_size, void* d_ws, size_t ws_size,
                              hipStream_t stream) {
    (void)in_sizes; (void)n_in; (void)out_size; (void)ws_size;

    const float* pose = (const float*)d_in[0];
    const float* eW0i = (const float*)d_in[1];
    const float* eW0h = (const float*)d_in[2];
    const float* eb0i = (const float*)d_in[3];
    const float* eb0h = (const float*)d_in[4];
    const float* eW1i = (const float*)d_in[5];
    const float* eW1h = (const float*)d_in[6];
    const float* eb1i = (const float*)d_in[7];
    const float* eb1h = (const float*)d_in[8];
    const float* dW0i = (const float*)d_in[9];
    const float* dW0h = (const float*)d_in[10];
    const float* db0i = (const float*)d_in[11];
    const float* db0h = (const float*)d_in[12];
    const float* dW1i = (const float*)d_in[13];
    const float* dW1h = (const float*)d_in[14];
    const float* db1i = (const float*)d_in[15];
    const float* db1h = (const float*)d_in[16];
    const float* oW   = (const float*)d_in[17];
    const float* ob   = (const float*)d_in[18];

    float* ws = (float*)d_ws;
    float* h0a = ws + OFF_H0A;
    float* h0b = ws + OFF_H0B;
    float* h1a = ws + OFF_H1A;
    float* h1b = ws + OFF_H1B;
    float* Wf  = ws + OFF_WF;
    float* bf  = ws + OFF_BF;
    unsigned* ctrs = (unsigned*)(ws + OFF_CTR);
    float* outf = (float*)d_out;

    hipMemsetAsync(d_ws, 0, 262144 * sizeof(float), stream);   // ping h0+h1 = 0
    hipMemsetAsync((void*)ctrs, 0, 32 * 64 * sizeof(unsigned), stream);

    fuse_wb<<<dim3(768), dim3(256), 0, stream>>>(dW0i, oW, ob, db0i, Wf, bf);

    void* kargs[] = {
        (void*)&pose,
        (void*)&eW0i, (void*)&eW0h, (void*)&eb0i, (void*)&eb0h,
        (void*)&eW1i, (void*)&eW1h, (void*)&eb1i, (void*)&eb1h,
        (void*)&dW0i, (void*)&dW0h, (void*)&db0i, (void*)&db0h,
        (void*)&dW1i, (void*)&dW1h, (void*)&db1i, (void*)&db1h,
        (void*)&oW, (void*)&ob,
        (void*)&outf,
        (void*)&h0a, (void*)&h0b, (void*)&h1a, (void*)&h1b,
        (void*)&Wf, (void*)&bf,
        (void*)&ctrs
    };
    hipLaunchCooperativeKernel((const void*)behav_main, dim3(256), dim3(512),
                               kargs, 0, stream);
}

// Round 8
// 3516.002 us; speedup vs baseline: 4.3299x; 1.5168x over previous
//
#include <hip/hip_runtime.h>
#include <cstddef>
#include <cstdint>

// ---------------------------------------------------------------------------
// GRU seq2seq via MFMA. fp16 weights (single copy) x fp16 hi/lo-split acts.
// 32 clusters x 16 samples; 8 WGs/cluster (32 units each); WG = 8 waves.
// Tile-ownership (no cross-wave K-reduce). Round-8 changes:
//  - __launch_bounds__(512,1): arg2 is CUDA-style min-blocks (r5/r6: (512,2)
//    capped VGPR at 128 -> spill); (512,1) -> 256 cap, frags fit.
//  - Gt[24][16][18] transposed-padded gate buffer: conflict-free epi reads.
//  - h exchange as packed {fp16 hi,lo} u32; fp32 h_prev lives in LDS (own
//    stripe never crosses WGs). Stage = 4x u64 agent loads/thread.
// ---------------------------------------------------------------------------

typedef __attribute__((ext_vector_type(8))) _Float16 half8v;
typedef __attribute__((ext_vector_type(4))) float float4v;

static const size_t OFF_H0A = 0;                    // 512*256 (packed u32 use)
static const size_t OFF_H1A = 131072;
static const size_t OFF_H0B = 262144;
static const size_t OFF_H1B = 393216;
static const size_t OFF_WF  = 524288;               // 768*256
static const size_t OFF_BF  = OFF_WF + 196608;      // 768 (pad 1024)
static const size_t OFF_CTR = OFF_BF + 1024;        // 32*64 uints

#define SIGF(x) (1.0f / (1.0f + __expf(-(x))))
#define MFMA16F __builtin_amdgcn_mfma_f32_16x16x32_f16
#define MM2(C, W, BH, BL) \
    C = MFMA16F(W, BH, C, 0, 0, 0); \
    C = MFMA16F(W, BL, C, 0, 0, 0);

__device__ __forceinline__ unsigned agent_ld32u(const unsigned* p) {
    return __hip_atomic_load(p, __ATOMIC_RELAXED, __HIP_MEMORY_SCOPE_AGENT);
}
__device__ __forceinline__ unsigned long long agent_ld64u(const unsigned long long* p) {
    return __hip_atomic_load(p, __ATOMIC_RELAXED, __HIP_MEMORY_SCOPE_AGENT);
}
__device__ __forceinline__ void agent_st32u(unsigned* p, unsigned v) {
    __hip_atomic_store(p, v, __ATOMIC_RELAXED, __HIP_MEMORY_SCOPE_AGENT);
}
__device__ __forceinline__ unsigned pack_h(float x) {
    _Float16 h = (_Float16)x;
    _Float16 l = (_Float16)(x - (float)h);
    unsigned short uh = __builtin_bit_cast(unsigned short, h);
    unsigned short ul = __builtin_bit_cast(unsigned short, l);
    return (unsigned)uh | ((unsigned)ul << 16);
}

// Wf = dec_Wih0 @ outW ; bf = dec_Wih0 @ out_b + dec_bih0
__global__ void fuse_wb(const float* __restrict__ Wih0, const float* __restrict__ oW,
                        const float* __restrict__ ob, const float* __restrict__ bih0,
                        float* __restrict__ Wf, float* __restrict__ bf) {
    int idx = blockIdx.x * 256 + threadIdx.x;
    int r = idx >> 8, h = idx & 255;
    const float* wr = Wih0 + (size_t)r * 128;
    float a = 0.f;
    for (int k = 0; k < 128; ++k) a = fmaf(wr[k], oW[(size_t)k * 256 + h], a);
    Wf[idx] = a;
    if (h == 0) {
        float b = 0.f;
        for (int k = 0; k < 128; ++k) b = fmaf(wr[k], ob[k], b);
        bf[r] = b + bih0[r];
    }
}

__global__ __launch_bounds__(512, 1)
void behav_main(
    const float* __restrict__ pose,
    const float* __restrict__ eW0i, const float* __restrict__ eW0h,
    const float* __restrict__ eb0i, const float* __restrict__ eb0h,
    const float* __restrict__ eW1i, const float* __restrict__ eW1h,
    const float* __restrict__ eb1i, const float* __restrict__ eb1h,
    const float* __restrict__ dW0i, const float* __restrict__ dW0h,
    const float* __restrict__ db0i, const float* __restrict__ db0h,
    const float* __restrict__ dW1i, const float* __restrict__ dW1h,
    const float* __restrict__ db1i, const float* __restrict__ db1h,
    const float* __restrict__ oW, const float* __restrict__ ob,
    float* __restrict__ out,
    float* h0a, float* h0b, float* h1a, float* h1b,
    const float* __restrict__ Wf, const float* __restrict__ bf,
    unsigned* ctrs)
{
    // SLOT A: h1_prev. SLOT B: h0. fp16 hi/lo, chunk-XOR swizzled.
    __shared__ _Float16 Ah[16][256], Al[16][256], Bh[16][256], Bl[16][256]; // 32 KB
    __shared__ float Gt[24 * 288];     // [slot][row 16][col 16 pad 18] 27.6 KB
    __shared__ float Hp0[16][32], Hp1[16][32];                              // 4 KB
    // Gt slots: W1: 0-5 p1 [r0,r1,z0,z1,n0i,n1i] | 22,23 p1 n0h,n1h
    //           6-17 p2 h-halves [tile*2+khalf] | 18,19 proj halves
    //      W2 (reuse): 0-3 p2 ri tiles | 4,5 ni k0-halves | 20,21 ni k1-halves

    const int tid = threadIdx.x;
    const int lane = tid & 63;
    const int w = tid >> 6;
    const int bid = blockIdx.x;
    const int xcd = bid & 7;
    const int inner = bid >> 3;
    const int uwg = inner & 7;
    const int c = ((inner >> 3) << 3) | xcd;    // XCD-pinned cluster
    const int s0 = c << 4, j0 = uwg << 5;
    unsigned* ctr = ctrs + (c << 6);
    unsigned epoch = 0;

    unsigned* h0pk[2] = { (unsigned*)h0a, (unsigned*)h0b };
    unsigned* h1pk[2] = { (unsigned*)h1a, (unsigned*)h1b };
    int pp = 0;

    const float4v FZ = {0.f, 0.f, 0.f, 0.f};
    const float obv = ((tid & 31) < 16) ? ob[(uwg << 4) + (tid & 31)] : 0.f;

    auto cbar = [&]() {
        __syncthreads();
        ++epoch;
        if (tid == 0) {
            __hip_atomic_fetch_add(ctr, 1u, __ATOMIC_RELAXED, __HIP_MEMORY_SCOPE_AGENT);
            unsigned tgt = epoch * 8u;
            while (__hip_atomic_load(ctr, __ATOMIC_RELAXED, __HIP_MEMORY_SCOPE_AGENT) < tgt)
                __builtin_amdgcn_s_sleep(1);
        }
        __syncthreads();
    };

    // weight frag: lane holds W[row0+(lane&15)][col0+(lane>>4)*8 ..+7] as fp16
    auto ldfrag = [&](const float* M, int ldm, int row0, int col0, half8v& wv) {
        const float* p = M + (size_t)(row0 + (lane & 15)) * ldm + col0 + ((lane >> 4) << 3);
        float4 a = *(const float4*)p;
        float4 b = *(const float4*)(p + 4);
        float vv[8] = {a.x, a.y, a.z, a.w, b.x, b.y, b.z, b.w};
        #pragma unroll
        for (int i = 0; i < 8; ++i) wv[i] = (_Float16)vv[i];
    };
    auto rdS = [&](const _Float16 (*arr)[256], int kloc) -> half8v {
        int s = lane & 15, o = lane >> 4;
        int phys = ((kloc << 2) + o) ^ (s & 7);
        return *(const half8v*)&arr[s][phys << 3];
    };
    auto rdX = [&](int t, int loc, half8v& bh, half8v& bl) {
        const float* p = pose + (size_t)(s0 + (lane & 15)) * 8192 + (size_t)t * 128
                         + (loc << 5) + ((lane >> 4) << 3);
        float4 a = *(const float4*)p;
        float4 b = *(const float4*)(p + 4);
        float vv[8] = {a.x, a.y, a.z, a.w, b.x, b.y, b.z, b.w};
        #pragma unroll
        for (int i = 0; i < 8; ++i) {
            _Float16 h = (_Float16)vv[i];
            bh[i] = h;
            bl[i] = (_Float16)(vv[i] - (float)h);
        }
    };
    // stage packed h: 4 x u64 agent loads -> 8 {hi,lo} pairs -> swizzled LDS
    auto stage = [&](_Float16 (*ha)[256], _Float16 (*la)[256], const unsigned* src) {
        int s = tid >> 5, cc = tid & 31;
        const unsigned long long* p =
            (const unsigned long long*)(src + (size_t)(s0 + s) * 256 + (cc << 3));
        unsigned long long q[4];
        #pragma unroll
        for (int i = 0; i < 4; ++i) q[i] = agent_ld64u(p + i);
        half8v hv, lv;
        #pragma unroll
        for (int i = 0; i < 4; ++i) {
            unsigned a = (unsigned)q[i], b = (unsigned)(q[i] >> 32);
            hv[2 * i]     = __builtin_bit_cast(_Float16, (unsigned short)(a & 0xFFFF));
            lv[2 * i]     = __builtin_bit_cast(_Float16, (unsigned short)(a >> 16));
            hv[2 * i + 1] = __builtin_bit_cast(_Float16, (unsigned short)(b & 0xFFFF));
            lv[2 * i + 1] = __builtin_bit_cast(_Float16, (unsigned short)(b >> 16));
        }
        int phys = cc ^ (s & 7);
        *(half8v*)&ha[s][phys << 3] = hv;
        *(half8v*)&la[s][phys << 3] = lv;
    };
    // gate buffer: transposed padded, conflict-free
    auto gdump = [&](int slot, float4v a) {
        int col = lane & 15, ro = (lane >> 4) << 2;
        float* b = &Gt[slot * 288 + ro * 18 + col];
        b[0] = a.x; b[18] = a.y; b[36] = a.z; b[54] = a.w;
    };
    auto gtr = [&](int slot, int r16, int s) -> float {
        return Gt[slot * 288 + r16 * 18 + s];
    };

    // ---- register-stationary weights: <=28 frags/wave ----
    half8v WA[16], WB[8], WC[4];
    float b0r, b0z, b0ni, b0nh, b1r, b1z, b1ni, b1nh;

    auto load_era = [&](const float* W0i, bool x128, const float* W0h,
                        const float* W1i, const float* W1h) {
        if (w < 6) {
            const int rb1 = ((w >> 1) << 8) + j0 + ((w & 1) << 4);
            if (x128) {
                #pragma unroll
                for (int cc = 0; cc < 4; ++cc) ldfrag(W0i, 128, rb1, cc << 5, WA[cc]);
            } else {
                #pragma unroll
                for (int cc = 0; cc < 8; ++cc) ldfrag(W0i, 256, rb1, cc << 5, WA[cc]);
            }
            #pragma unroll
            for (int cc = 0; cc < 8; ++cc) ldfrag(W0h, 256, rb1, cc << 5, WA[8 + cc]);
            const int t2 = w >> 1;
            const int rb2 = ((t2 >> 1) << 8) + j0 + ((t2 & 1) << 4);
            const int kb = (w & 1) << 2;
            #pragma unroll
            for (int cc = 0; cc < 4; ++cc) ldfrag(W1h, 256, rb2, (kb + cc) << 5, WC[cc]);
            if (w < 4) {
                #pragma unroll
                for (int cc = 0; cc < 8; ++cc) ldfrag(W1i, 256, rb1, cc << 5, WB[cc]);
            } else {
                const int rb3 = 512 + j0 + ((w - 4) << 4);
                #pragma unroll
                for (int cc = 0; cc < 4; ++cc) ldfrag(W1i, 256, rb3, cc << 5, WB[cc]);
            }
        } else {
            #pragma unroll
            for (int j = 0; j < 3; ++j) {
                const int hh = 6 + (w - 6) * 3 + j;
                const int t2 = hh >> 1;
                const int rb2 = ((t2 >> 1) << 8) + j0 + ((t2 & 1) << 4);
                const int kb = (hh & 1) << 2;
                #pragma unroll
                for (int cc = 0; cc < 4; ++cc)
                    ldfrag(W1h, 256, rb2, (kb + cc) << 5, WA[4 * j + cc]);
            }
            #pragma unroll
            for (int cc = 0; cc < 4; ++cc)
                ldfrag(oW, 256, uwg << 4, (((w - 6) << 2) + cc) << 5, WA[12 + cc]);
            const int rb3 = 512 + j0 + ((w - 6) << 4);
            #pragma unroll
            for (int cc = 0; cc < 4; ++cc) ldfrag(W1i, 256, rb3, (4 + cc) << 5, WB[cc]);
        }
    };
    auto ldb0 = [&](const float* bi, const float* bhh) {
        int jj = j0 + (tid & 31);
        b0r = bi[jj] + bhh[jj]; b0z = bi[256 + jj] + bhh[256 + jj];
        b0ni = bi[512 + jj]; b0nh = bhh[512 + jj];
    };
    auto ldb1 = [&](const float* bi, const float* bhh) {
        int jj = j0 + (tid & 31);
        b1r = bi[jj] + bhh[jj]; b1z = bi[256 + jj] + bhh[256 + jj];
        b1ni = bi[512 + jj]; b1nh = bhh[512 + jj];
    };

    // ---- windows ----
    auto W1_fn = [&](int t, bool xs, bool pj) {
        if (w < 6) {
            float4v accI = FZ, accH = FZ;
            if (xs) {
                #pragma unroll
                for (int cc = 0; cc < 4; ++cc) {
                    half8v bh, bl; rdX(t, cc, bh, bl);
                    MM2(accI, WA[cc], bh, bl);
                }
            } else {
                #pragma unroll
                for (int cc = 0; cc < 8; ++cc) {
                    half8v bh = rdS(Ah, cc), bl = rdS(Al, cc);
                    MM2(accI, WA[cc], bh, bl);
                }
            }
            if (w >= 4) {
                #pragma unroll
                for (int cc = 0; cc < 8; ++cc) {
                    half8v bh = rdS(Bh, cc), bl = rdS(Bl, cc);
                    MM2(accH, WA[8 + cc], bh, bl);
                }
                gdump(w, accI);
                gdump(22 + (w - 4), accH);
            } else {
                #pragma unroll
                for (int cc = 0; cc < 8; ++cc) {
                    half8v bh = rdS(Bh, cc), bl = rdS(Bl, cc);
                    MM2(accI, WA[8 + cc], bh, bl);
                }
                gdump(w, accI);
            }
            float4v accP = FZ;
            const int kb = (w & 1) << 2;
            #pragma unroll
            for (int cc = 0; cc < 4; ++cc) {
                half8v bh = rdS(Ah, kb + cc), bl = rdS(Al, kb + cc);
                MM2(accP, WC[cc], bh, bl);
            }
            gdump(6 + w, accP);
        } else {
            #pragma unroll
            for (int j = 0; j < 3; ++j) {
                const int hh = 6 + (w - 6) * 3 + j;
                const int kb = (hh & 1) << 2;
                float4v accP = FZ;
                #pragma unroll
                for (int cc = 0; cc < 4; ++cc) {
                    half8v bh = rdS(Ah, kb + cc), bl = rdS(Al, kb + cc);
                    MM2(accP, WA[4 * j + cc], bh, bl);
                }
                gdump(6 + hh, accP);
            }
            if (pj) {
                float4v accJ = FZ;
                const int cb = (w - 6) << 2;
                #pragma unroll
                for (int cc = 0; cc < 4; ++cc) {
                    half8v bh = rdS(Ah, cb + cc), bl = rdS(Al, cb + cc);
                    MM2(accJ, WA[12 + cc], bh, bl);
                }
                gdump(18 + (w - 6), accJ);
            }
        }
    };
    auto W2_fn = [&]() {
        if (w < 4) {
            float4v acc = FZ;
            #pragma unroll
            for (int cc = 0; cc < 8; ++cc) {
                half8v bh = rdS(Bh, cc), bl = rdS(Bl, cc);
                MM2(acc, WB[cc], bh, bl);
            }
            gdump(w, acc);
        } else {
            float4v acc = FZ;
            const int kb = (w >= 6) ? 4 : 0;
            #pragma unroll
            for (int cc = 0; cc < 4; ++cc) {
                half8v bh = rdS(Bh, kb + cc), bl = rdS(Bl, kb + cc);
                MM2(acc, WB[cc], bh, bl);
            }
            const int sl = (w == 4) ? 4 : (w == 5) ? 20 : (w == 6) ? 5 : 21;
            gdump(sl, acc);
        }
    };
    auto epi1 = [&](unsigned* pongpk) {
        int s = tid >> 5, ul = tid & 31, t2 = ul >> 4, r16 = ul & 15;
        float r = SIGF(gtr(t2, r16, s) + b0r);
        float z = SIGF(gtr(2 + t2, r16, s) + b0z);
        float n = tanhf(gtr(4 + t2, r16, s) + b0ni + r * (gtr(22 + t2, r16, s) + b0nh));
        float h = (1.f - z) * n + z * Hp0[s][ul];
        Hp0[s][ul] = h;
        agent_st32u(pongpk + (size_t)(s0 + s) * 256 + j0 + ul, pack_h(h));
    };
    auto epi2 = [&](unsigned* pongpk) {
        int s = tid >> 5, ul = tid & 31, t2 = ul >> 4, r16 = ul & 15;
        float r = SIGF(gtr(t2, r16, s) + gtr(6 + (t2 << 1), r16, s)
                       + gtr(7 + (t2 << 1), r16, s) + b1r);
        float z = SIGF(gtr(2 + t2, r16, s) + gtr(10 + (t2 << 1), r16, s)
                       + gtr(11 + (t2 << 1), r16, s) + b1z);
        int nia = t2 ? 20 : 4, nib = t2 ? 21 : 5;
        float ni = gtr(nia, r16, s) + gtr(nib, r16, s);
        float nh = gtr(14 + (t2 << 1), r16, s) + gtr(15 + (t2 << 1), r16, s);
        float n = tanhf(ni + b1ni + r * (nh + b1nh));
        float h = (1.f - z) * n + z * Hp1[s][ul];
        Hp1[s][ul] = h;
        agent_st32u(pongpk + (size_t)(s0 + s) * 256 + j0 + ul, pack_h(h));
    };
    auto epi_proj = [&](int tq) {
        int s = tid >> 5, ul = tid & 31;
        if (ul < 16) {
            float v = gtr(18, ul, s) + gtr(19, ul, s) + obv;
            out[(size_t)(s0 + s) * 65536 + (size_t)tq * 128 + (uwg << 4) + ul] = v;
        }
    };

    auto step = [&](int t, bool xs, bool pj) {
        W1_fn(t, xs, pj);
        __syncthreads();                    // sync1: W1 dumps visible
        epi1(h0pk[pp ^ 1]);
        if (pj) epi_proj(t - 1);
        cbar();                             // cbar1: h0_new global-visible
        stage(Bh, Bl, h0pk[pp ^ 1]);
        __syncthreads();                    // sync2: slot B = h0_new ready
        W2_fn();
        __syncthreads();                    // sync3: W2 dumps visible
        epi2(h1pk[pp ^ 1]);
        cbar();                             // cbar2: h1_new global-visible
        stage(Ah, Al, h1pk[pp ^ 1]);
        __syncthreads();                    // sync4: slot A = h1_new ready
        pp ^= 1;
    };

    // ---- init ----
    {
        int s = tid >> 5, cc = tid & 31;
        half8v z;
        #pragma unroll
        for (int i = 0; i < 8; ++i) z[i] = (_Float16)0.f;
        *(half8v*)&Ah[s][cc << 3] = z;
        *(half8v*)&Al[s][cc << 3] = z;
        *(half8v*)&Bh[s][cc << 3] = z;
        *(half8v*)&Bl[s][cc << 3] = z;
        Hp0[s][cc] = 0.f;
        Hp1[s][cc] = 0.f;
    }
    __syncthreads();

    // ===================== ENCODER =====================
    load_era(eW0i, true, eW0h, eW1i, eW1h);
    ldb0(eb0i, eb0h); ldb1(eb1i, eb1h);
    for (int t = 0; t < 64; ++t) step(t, true, false);

    // ===================== DECODER: teacher =====================
    load_era(dW0i, true, dW0h, dW1i, dW1h);
    ldb0(db0i, db0h); ldb1(db1i, db1h);
    step(0, true, false);
    for (int t = 1; t < 64; ++t) step(t, true, true);

    // ===================== DECODER: autoregressive =====================
    if (w < 6) {
        const int rb1 = ((w >> 1) << 8) + j0 + ((w & 1) << 4);
        #pragma unroll
        for (int cc = 0; cc < 8; ++cc) ldfrag(Wf, 256, rb1, cc << 5, WA[cc]);
    }
    {
        int jj = j0 + (tid & 31);
        b0r = bf[jj] + db0h[jj];
        b0z = bf[256 + jj] + db0h[256 + jj];
        b0ni = bf[512 + jj];
        b0nh = db0h[512 + jj];
    }
    for (int t = 64; t < 512; ++t) step(t, false, true);

    // ===================== tail: out[511] = proj(h1_511) =====================
    if (w >= 6) {
        float4v accJ = FZ;
        const int cb = (w - 6) << 2;
        #pragma unroll
        for (int cc = 0; cc < 4; ++cc) {
            half8v bh = rdS(Ah, cb + cc), bl = rdS(Al, cb + cc);
            MM2(accJ, WA[12 + cc], bh, bl);
        }
        gdump(18 + (w - 6), accJ);
    }
    __syncthreads();
    epi_proj(511);
}

extern "C" void kernel_launch(void* const* d_in, const int* in_sizes, int n_in,
                              void* d_out, int out_size, void* d_ws, size_t ws_size,
                              hipStream_t stream) {
    (void)in_sizes; (void)n_in; (void)out_size; (void)ws_size;

    const float* pose = (const float*)d_in[0];
    const float* eW0i = (const float*)d_in[1];
    const float* eW0h = (const float*)d_in[2];
    const float* eb0i = (const float*)d_in[3];
    const float* eb0h = (const float*)d_in[4];
    const float* eW1i = (const float*)d_in[5];
    const float* eW1h = (const float*)d_in[6];
    const float* eb1i = (const float*)d_in[7];
    const float* eb1h = (const float*)d_in[8];
    const float* dW0i = (const float*)d_in[9];
    const float* dW0h = (const float*)d_in[10];
    const float* db0i = (const float*)d_in[11];
    const float* db0h = (const float*)d_in[12];
    const float* dW1i = (const float*)d_in[13];
    const float* dW1h = (const float*)d_in[14];
    const float* db1i = (const float*)d_in[15];
    const float* db1h = (const float*)d_in[16];
    const float* oW   = (const float*)d_in[17];
    const float* ob   = (const float*)d_in[18];

    float* ws = (float*)d_ws;
    float* h0a = ws + OFF_H0A;
    float* h0b = ws + OFF_H0B;
    float* h1a = ws + OFF_H1A;
    float* h1b = ws + OFF_H1B;
    float* Wf  = ws + OFF_WF;
    float* bf  = ws + OFF_BF;
    unsigned* ctrs = (unsigned*)(ws + OFF_CTR);
    float* outf = (float*)d_out;

    hipMemsetAsync(d_ws, 0, 262144 * sizeof(float), stream);   // ping h0+h1 = 0
    hipMemsetAsync((void*)ctrs, 0, 32 * 64 * sizeof(unsigned), stream);

    fuse_wb<<<dim3(768), dim3(256), 0, stream>>>(dW0i, oW, ob, db0i, Wf, bf);

    void* kargs[] = {
        (void*)&pose,
        (void*)&eW0i, (void*)&eW0h, (void*)&eb0i, (void*)&eb0h,
        (void*)&eW1i, (void*)&eW1h, (void*)&eb1i, (void*)&eb1h,
        (void*)&dW0i, (void*)&dW0h, (void*)&db0i, (void*)&db0h,
        (void*)&dW1i, (void*)&dW1h, (void*)&db1i, (void*)&db1h,
        (void*)&oW, (void*)&ob,
        (void*)&outf,
        (void*)&h0a, (void*)&h0b, (void*)&h1a, (void*)&h1b,
        (void*)&Wf, (void*)&bf,
        (void*)&ctrs
    };
    hipLaunchCooperativeKernel((const void*)behav_main, dim3(256), dim3(512),
                               kargs, 0, stream);
}

// Round 10
// 3197.039 us; speedup vs baseline: 4.7619x; 1.0998x over previous
//
#include <hip/hip_runtime.h>
#include <cstddef>
#include <cstdint>

// ---------------------------------------------------------------------------
// GRU seq2seq via MFMA. fp16 weights (single copy) x fp16 hi/lo-split acts.
// 32 clusters x 16 samples; 8 WGs/cluster (32 units each); WG = 8 waves.
// Tile-ownership, register-stationary weights (<=28 frags/wave).
// Round-10: DYNAMIC XCD clustering. r9 hung because bid%8->XCD round-robin
// was assumed; made correctness-critical it broke. Now each WG reads its
// physical XCD via s_getreg(HW_REG_XCC_ID) and claims a slot in a per-XCD
// counter -> clusters are XCD-local BY CONSTRUCTION. Data path stays L2
// (plain h stores + sc0 stage loads); barrier reverts to the r8-proven
// MALL agent-atomic add/poll (replay-safe, mapping-independent).
// ---------------------------------------------------------------------------

typedef __attribute__((ext_vector_type(8))) _Float16 half8v;
typedef __attribute__((ext_vector_type(4))) float float4v;
typedef __attribute__((ext_vector_type(4))) unsigned uint4v;

static const size_t OFF_H0A = 0;                    // 512*256 (packed u32)
static const size_t OFF_H1A = 131072;
static const size_t OFF_H0B = 262144;
static const size_t OFF_H1B = 393216;
static const size_t OFF_WF  = 524288;               // 768*256
static const size_t OFF_BF  = OFF_WF + 196608;      // 768 (pad 1024)
static const size_t OFF_CTR = OFF_BF + 1024;        // 32*64 uints (barrier ctrs)
static const size_t OFF_CLM = OFF_CTR + 2048;       // 8 uints (XCD claim), pad 64

#define SIGF(x) (1.0f / (1.0f + __expf(-(x))))
#define MFMA16F __builtin_amdgcn_mfma_f32_16x16x32_f16
#define MM2(C, W, BH, BL) \
    C = MFMA16F(W, BH, C, 0, 0, 0); \
    C = MFMA16F(W, BL, C, 0, 0, 0);

__device__ __forceinline__ unsigned pack_h(float x) {
    _Float16 h = (_Float16)x;
    _Float16 l = (_Float16)(x - (float)h);
    unsigned short uh = __builtin_bit_cast(unsigned short, h);
    unsigned short ul = __builtin_bit_cast(unsigned short, l);
    return (unsigned)uh | ((unsigned)ul << 16);
}

// 32B sc0 load: bypass L1, read the XCD-shared L2 (fresh vs other CUs).
__device__ __forceinline__ void ld32_sc0(const void* p, uint4v& a, uint4v& b) {
    asm volatile("global_load_dwordx4 %0, %2, off sc0\n\t"
                 "global_load_dwordx4 %1, %2, off offset:16 sc0\n\t"
                 "s_waitcnt vmcnt(0)"
                 : "=v"(a), "=v"(b) : "v"(p) : "memory");
}

// Wf = dec_Wih0 @ outW ; bf = dec_Wih0 @ out_b + dec_bih0
__global__ void fuse_wb(const float* __restrict__ Wih0, const float* __restrict__ oW,
                        const float* __restrict__ ob, const float* __restrict__ bih0,
                        float* __restrict__ Wf, float* __restrict__ bf) {
    int idx = blockIdx.x * 256 + threadIdx.x;
    int r = idx >> 8, h = idx & 255;
    const float* wr = Wih0 + (size_t)r * 128;
    float a = 0.f;
    for (int k = 0; k < 128; ++k) a = fmaf(wr[k], oW[(size_t)k * 256 + h], a);
    Wf[idx] = a;
    if (h == 0) {
        float b = 0.f;
        for (int k = 0; k < 128; ++k) b = fmaf(wr[k], ob[k], b);
        bf[r] = b + bih0[r];
    }
}

__global__ __launch_bounds__(512, 1)
void behav_main(
    const float* __restrict__ pose,
    const float* __restrict__ eW0i, const float* __restrict__ eW0h,
    const float* __restrict__ eb0i, const float* __restrict__ eb0h,
    const float* __restrict__ eW1i, const float* __restrict__ eW1h,
    const float* __restrict__ eb1i, const float* __restrict__ eb1h,
    const float* __restrict__ dW0i, const float* __restrict__ dW0h,
    const float* __restrict__ db0i, const float* __restrict__ db0h,
    const float* __restrict__ dW1i, const float* __restrict__ dW1h,
    const float* __restrict__ db1i, const float* __restrict__ db1h,
    const float* __restrict__ oW, const float* __restrict__ ob,
    float* __restrict__ out,
    float* h0a, float* h0b, float* h1a, float* h1b,
    const float* __restrict__ Wf, const float* __restrict__ bf,
    unsigned* ctrs, unsigned* clm)
{
    // SLOT A: h1_prev. SLOT B: h0. fp16 hi/lo, chunk-XOR swizzled.
    __shared__ _Float16 Ah[16][256], Al[16][256], Bh[16][256], Bl[16][256]; // 32 KB
    __shared__ float Gt[24 * 288];     // [slot][row 16][col 16 pad 18] 27.6 KB
    __shared__ float Hp0[16][32], Hp1[16][32];                              // 4 KB
    __shared__ unsigned s_lin;

    const int tid = threadIdx.x;
    const int lane = tid & 63;
    const int w = tid >> 6;

    // -------- dynamic XCD-local cluster formation --------
    if (tid == 0) {
        unsigned xcc;
        asm volatile("s_getreg_b32 %0, hwreg(HW_REG_XCC_ID)" : "=s"(xcc));
        xcc &= 7u;
        unsigned pos = __hip_atomic_fetch_add(&clm[xcc], 1u,
                           __ATOMIC_RELAXED, __HIP_MEMORY_SCOPE_AGENT);
        s_lin = (xcc << 5) | (pos & 31u);
    }
    __syncthreads();
    const unsigned lin = s_lin;
    const int c = (int)(lin >> 3);              // [0,32): xcc*4 + pos/8
    const int uwg = (int)(lin & 7);             // [0,8)
    const int s0 = c << 4, j0 = uwg << 5;
    unsigned* ctr = ctrs + (c << 6);            // MALL barrier counter
    unsigned epoch = 0;

    unsigned* h0pk[2] = { (unsigned*)h0a, (unsigned*)h0b };
    unsigned* h1pk[2] = { (unsigned*)h1a, (unsigned*)h1b };
    int pp = 0;

    const float4v FZ = {0.f, 0.f, 0.f, 0.f};
    const float obv = ((tid & 31) < 16) ? ob[(uwg << 4) + (tid & 31)] : 0.f;

    // Barrier at MALL (r8-proven): syncthreads drains vmcnt (h stores L2-acked
    // before arrival); arrive/poll via agent atomics (mapping-independent).
    auto cbar = [&]() {
        __syncthreads();
        ++epoch;
        if (tid == 0) {
            __hip_atomic_fetch_add(ctr, 1u, __ATOMIC_RELAXED, __HIP_MEMORY_SCOPE_AGENT);
            unsigned tgt = epoch * 8u;
            while (__hip_atomic_load(ctr, __ATOMIC_RELAXED, __HIP_MEMORY_SCOPE_AGENT) < tgt)
                __builtin_amdgcn_s_sleep(1);
        }
        __syncthreads();
    };

    // weight frag: lane holds W[row0+(lane&15)][col0+(lane>>4)*8 ..+7] as fp16
    auto ldfrag = [&](const float* M, int ldm, int row0, int col0, half8v& wv) {
        const float* p = M + (size_t)(row0 + (lane & 15)) * ldm + col0 + ((lane >> 4) << 3);
        float4 a = *(const float4*)p;
        float4 b = *(const float4*)(p + 4);
        float vv[8] = {a.x, a.y, a.z, a.w, b.x, b.y, b.z, b.w};
        #pragma unroll
        for (int i = 0; i < 8; ++i) wv[i] = (_Float16)vv[i];
    };
    auto rdS = [&](const _Float16 (*arr)[256], int kloc) -> half8v {
        int s = lane & 15, o = lane >> 4;
        int phys = ((kloc << 2) + o) ^ (s & 7);
        return *(const half8v*)&arr[s][phys << 3];
    };
    auto rdX = [&](int t, int loc, half8v& bh, half8v& bl) {
        const float* p = pose + (size_t)(s0 + (lane & 15)) * 8192 + (size_t)t * 128
                         + (loc << 5) + ((lane >> 4) << 3);
        float4 a = *(const float4*)p;
        float4 b = *(const float4*)(p + 4);
        float vv[8] = {a.x, a.y, a.z, a.w, b.x, b.y, b.z, b.w};
        #pragma unroll
        for (int i = 0; i < 8; ++i) {
            _Float16 h = (_Float16)vv[i];
            bh[i] = h;
            bl[i] = (_Float16)(vv[i] - (float)h);
        }
    };
    // stage packed h: 2 x dwordx4 sc0 loads (shared L2) -> swizzled LDS
    auto stage = [&](_Float16 (*ha)[256], _Float16 (*la)[256], const unsigned* src) {
        int s = tid >> 5, cc = tid & 31;
        uint4v a, b;
        ld32_sc0((const void*)(src + (size_t)(s0 + s) * 256 + (cc << 3)), a, b);
        unsigned u[8] = {a.x, a.y, a.z, a.w, b.x, b.y, b.z, b.w};
        half8v hv, lv;
        #pragma unroll
        for (int i = 0; i < 8; ++i) {
            hv[i] = __builtin_bit_cast(_Float16, (unsigned short)(u[i] & 0xFFFF));
            lv[i] = __builtin_bit_cast(_Float16, (unsigned short)(u[i] >> 16));
        }
        int phys = cc ^ (s & 7);
        *(half8v*)&ha[s][phys << 3] = hv;
        *(half8v*)&la[s][phys << 3] = lv;
    };
    auto gdump = [&](int slot, float4v a) {
        int col = lane & 15, ro = (lane >> 4) << 2;
        float* b = &Gt[slot * 288 + ro * 18 + col];
        b[0] = a.x; b[18] = a.y; b[36] = a.z; b[54] = a.w;
    };
    auto gtr = [&](int slot, int r16, int s) -> float {
        return Gt[slot * 288 + r16 * 18 + s];
    };

    // ---- register-stationary weights: <=28 frags/wave ----
    half8v WA[16], WB[8], WC[4];
    float b0r, b0z, b0ni, b0nh, b1r, b1z, b1ni, b1nh;

    auto load_era = [&](const float* W0i, bool x128, const float* W0h,
                        const float* W1i, const float* W1h) {
        if (w < 6) {
            const int rb1 = ((w >> 1) << 8) + j0 + ((w & 1) << 4);
            if (x128) {
                #pragma unroll
                for (int cc = 0; cc < 4; ++cc) ldfrag(W0i, 128, rb1, cc << 5, WA[cc]);
            } else {
                #pragma unroll
                for (int cc = 0; cc < 8; ++cc) ldfrag(W0i, 256, rb1, cc << 5, WA[cc]);
            }
            #pragma unroll
            for (int cc = 0; cc < 8; ++cc) ldfrag(W0h, 256, rb1, cc << 5, WA[8 + cc]);
            const int t2 = w >> 1;
            const int rb2 = ((t2 >> 1) << 8) + j0 + ((t2 & 1) << 4);
            const int kb = (w & 1) << 2;
            #pragma unroll
            for (int cc = 0; cc < 4; ++cc) ldfrag(W1h, 256, rb2, (kb + cc) << 5, WC[cc]);
            if (w < 4) {
                #pragma unroll
                for (int cc = 0; cc < 8; ++cc) ldfrag(W1i, 256, rb1, cc << 5, WB[cc]);
            } else {
                const int rb3 = 512 + j0 + ((w - 4) << 4);
                #pragma unroll
                for (int cc = 0; cc < 4; ++cc) ldfrag(W1i, 256, rb3, cc << 5, WB[cc]);
            }
        } else {
            #pragma unroll
            for (int j = 0; j < 3; ++j) {
                const int hh = 6 + (w - 6) * 3 + j;
                const int t2 = hh >> 1;
                const int rb2 = ((t2 >> 1) << 8) + j0 + ((t2 & 1) << 4);
                const int kb = (hh & 1) << 2;
                #pragma unroll
                for (int cc = 0; cc < 4; ++cc)
                    ldfrag(W1h, 256, rb2, (kb + cc) << 5, WA[4 * j + cc]);
            }
            #pragma unroll
            for (int cc = 0; cc < 4; ++cc)
                ldfrag(oW, 256, uwg << 4, (((w - 6) << 2) + cc) << 5, WA[12 + cc]);
            const int rb3 = 512 + j0 + ((w - 6) << 4);
            #pragma unroll
            for (int cc = 0; cc < 4; ++cc) ldfrag(W1i, 256, rb3, (4 + cc) << 5, WB[cc]);
        }
    };
    auto ldb0 = [&](const float* bi, const float* bhh) {
        int jj = j0 + (tid & 31);
        b0r = bi[jj] + bhh[jj]; b0z = bi[256 + jj] + bhh[256 + jj];
        b0ni = bi[512 + jj]; b0nh = bhh[512 + jj];
    };
    auto ldb1 = [&](const float* bi, const float* bhh) {
        int jj = j0 + (tid & 31);
        b1r = bi[jj] + bhh[jj]; b1z = bi[256 + jj] + bhh[256 + jj];
        b1ni = bi[512 + jj]; b1nh = bhh[512 + jj];
    };

    // ---- windows ----
    auto W1_fn = [&](int t, bool xs, bool pj) {
        if (w < 6) {
            float4v accI = FZ, accH = FZ;
            if (xs) {
                #pragma unroll
                for (int cc = 0; cc < 4; ++cc) {
                    half8v bh, bl; rdX(t, cc, bh, bl);
                    MM2(accI, WA[cc], bh, bl);
                }
            } else {
                #pragma unroll
                for (int cc = 0; cc < 8; ++cc) {
                    half8v bh = rdS(Ah, cc), bl = rdS(Al, cc);
                    MM2(accI, WA[cc], bh, bl);
                }
            }
            if (w >= 4) {
                #pragma unroll
                for (int cc = 0; cc < 8; ++cc) {
                    half8v bh = rdS(Bh, cc), bl = rdS(Bl, cc);
                    MM2(accH, WA[8 + cc], bh, bl);
                }
                gdump(w, accI);
                gdump(22 + (w - 4), accH);
            } else {
                #pragma unroll
                for (int cc = 0; cc < 8; ++cc) {
                    half8v bh = rdS(Bh, cc), bl = rdS(Bl, cc);
                    MM2(accI, WA[8 + cc], bh, bl);
                }
                gdump(w, accI);
            }
            float4v accP = FZ;
            const int kb = (w & 1) << 2;
            #pragma unroll
            for (int cc = 0; cc < 4; ++cc) {
                half8v bh = rdS(Ah, kb + cc), bl = rdS(Al, kb + cc);
                MM2(accP, WC[cc], bh, bl);
            }
            gdump(6 + w, accP);
        } else {
            #pragma unroll
            for (int j = 0; j < 3; ++j) {
                const int hh = 6 + (w - 6) * 3 + j;
                const int kb = (hh & 1) << 2;
                float4v accP = FZ;
                #pragma unroll
                for (int cc = 0; cc < 4; ++cc) {
                    half8v bh = rdS(Ah, kb + cc), bl = rdS(Al, kb + cc);
                    MM2(accP, WA[4 * j + cc], bh, bl);
                }
                gdump(6 + hh, accP);
            }
            if (pj) {
                float4v accJ = FZ;
                const int cb = (w - 6) << 2;
                #pragma unroll
                for (int cc = 0; cc < 4; ++cc) {
                    half8v bh = rdS(Ah, cb + cc), bl = rdS(Al, cb + cc);
                    MM2(accJ, WA[12 + cc], bh, bl);
                }
                gdump(18 + (w - 6), accJ);
            }
        }
    };
    auto W2_fn = [&]() {
        if (w < 4) {
            float4v acc = FZ;
            #pragma unroll
            for (int cc = 0; cc < 8; ++cc) {
                half8v bh = rdS(Bh, cc), bl = rdS(Bl, cc);
                MM2(acc, WB[cc], bh, bl);
            }
            gdump(w, acc);
        } else {
            float4v acc = FZ;
            const int kb = (w >= 6) ? 4 : 0;
            #pragma unroll
            for (int cc = 0; cc < 4; ++cc) {
                half8v bh = rdS(Bh, kb + cc), bl = rdS(Bl, kb + cc);
                MM2(acc, WB[cc], bh, bl);
            }
            const int sl = (w == 4) ? 4 : (w == 5) ? 20 : (w == 6) ? 5 : 21;
            gdump(sl, acc);
        }
    };
    auto epi1 = [&](unsigned* pongpk) {
        int s = tid >> 5, ul = tid & 31, t2 = ul >> 4, r16 = ul & 15;
        float r = SIGF(gtr(t2, r16, s) + b0r);
        float z = SIGF(gtr(2 + t2, r16, s) + b0z);
        float n = tanhf(gtr(4 + t2, r16, s) + b0ni + r * (gtr(22 + t2, r16, s) + b0nh));
        float h = (1.f - z) * n + z * Hp0[s][ul];
        Hp0[s][ul] = h;
        pongpk[(size_t)(s0 + s) * 256 + j0 + ul] = pack_h(h);   // plain store -> L2
    };
    auto epi2 = [&](unsigned* pongpk) {
        int s = tid >> 5, ul = tid & 31, t2 = ul >> 4, r16 = ul & 15;
        float r = SIGF(gtr(t2, r16, s) + gtr(6 + (t2 << 1), r16, s)
                       + gtr(7 + (t2 << 1), r16, s) + b1r);
        float z = SIGF(gtr(2 + t2, r16, s) + gtr(10 + (t2 << 1), r16, s)
                       + gtr(11 + (t2 << 1), r16, s) + b1z);
        int nia = t2 ? 20 : 4, nib = t2 ? 21 : 5;
        float ni = gtr(nia, r16, s) + gtr(nib, r16, s);
        float nh = gtr(14 + (t2 << 1), r16, s) + gtr(15 + (t2 << 1), r16, s);
        float n = tanhf(ni + b1ni + r * (nh + b1nh));
        float h = (1.f - z) * n + z * Hp1[s][ul];
        Hp1[s][ul] = h;
        pongpk[(size_t)(s0 + s) * 256 + j0 + ul] = pack_h(h);   // plain store -> L2
    };
    auto epi_proj = [&](int tq) {
        int s = tid >> 5, ul = tid & 31;
        if (ul < 16) {
            float v = gtr(18, ul, s) + gtr(19, ul, s) + obv;
            out[(size_t)(s0 + s) * 65536 + (size_t)tq * 128 + (uwg << 4) + ul] = v;
        }
    };

    auto step = [&](int t, bool xs, bool pj) {
        W1_fn(t, xs, pj);
        __syncthreads();                    // sync1: Gt dumps visible
        epi1(h0pk[pp ^ 1]);
        cbar();                             // cbar1: h0_new L2-visible
        stage(Bh, Bl, h0pk[pp ^ 1]);
        if (pj) epi_proj(t - 1);            // off the cbar1-arrival path
        __syncthreads();                    // sync2: slot B = h0_new ready
        W2_fn();
        __syncthreads();                    // sync3: W2 dumps visible
        epi2(h1pk[pp ^ 1]);
        cbar();                             // cbar2: h1_new L2-visible
        stage(Ah, Al, h1pk[pp ^ 1]);
        __syncthreads();                    // sync4: slot A = h1_new ready
        pp ^= 1;
    };

    // ---- init ----
    {
        int s = tid >> 5, cc = tid & 31;
        half8v z;
        #pragma unroll
        for (int i = 0; i < 8; ++i) z[i] = (_Float16)0.f;
        *(half8v*)&Ah[s][cc << 3] = z;
        *(half8v*)&Al[s][cc << 3] = z;
        *(half8v*)&Bh[s][cc << 3] = z;
        *(half8v*)&Bl[s][cc << 3] = z;
        Hp0[s][cc] = 0.f;
        Hp1[s][cc] = 0.f;
    }
    __syncthreads();

    // ===================== ENCODER =====================
    load_era(eW0i, true, eW0h, eW1i, eW1h);
    ldb0(eb0i, eb0h); ldb1(eb1i, eb1h);
    for (int t = 0; t < 64; ++t) step(t, true, false);

    // ===================== DECODER: teacher =====================
    load_era(dW0i, true, dW0h, dW1i, dW1h);
    ldb0(db0i, db0h); ldb1(db1i, db1h);
    step(0, true, false);
    for (int t = 1; t < 64; ++t) step(t, true, true);

    // ===================== DECODER: autoregressive =====================
    if (w < 6) {
        const int rb1 = ((w >> 1) << 8) + j0 + ((w & 1) << 4);
        #pragma unroll
        for (int cc = 0; cc < 8; ++cc) ldfrag(Wf, 256, rb1, cc << 5, WA[cc]);
    }
    {
        int jj = j0 + (tid & 31);
        b0r = bf[jj] + db0h[jj];
        b0z = bf[256 + jj] + db0h[256 + jj];
        b0ni = bf[512 + jj];
        b0nh = db0h[512 + jj];
    }
    for (int t = 64; t < 512; ++t) step(t, false, true);

    // ===================== tail: out[511] = proj(h1_511) =====================
    if (w >= 6) {
        float4v accJ = FZ;
        const int cb = (w - 6) << 2;
        #pragma unroll
        for (int cc = 0; cc < 4; ++cc) {
            half8v bh = rdS(Ah, cb + cc), bl = rdS(Al, cb + cc);
            MM2(accJ, WA[12 + cc], bh, bl);
        }
        gdump(18 + (w - 6), accJ);
    }
    __syncthreads();
    epi_proj(511);
}

extern "C" void kernel_launch(void* const* d_in, const int* in_sizes, int n_in,
                              void* d_out, int out_size, void* d_ws, size_t ws_size,
                              hipStream_t stream) {
    (void)in_sizes; (void)n_in; (void)out_size; (void)ws_size;

    const float* pose = (const float*)d_in[0];
    const float* eW0i = (const float*)d_in[1];
    const float* eW0h = (const float*)d_in[2];
    const float* eb0i = (const float*)d_in[3];
    const float* eb0h = (const float*)d_in[4];
    const float* eW1i = (const float*)d_in[5];
    const float* eW1h = (const float*)d_in[6];
    const float* eb1i = (const float*)d_in[7];
    const float* eb1h = (const float*)d_in[8];
    const float* dW0i = (const float*)d_in[9];
    const float* dW0h = (const float*)d_in[10];
    const float* db0i = (const float*)d_in[11];
    const float* db0h = (const float*)d_in[12];
    const float* dW1i = (const float*)d_in[13];
    const float* dW1h = (const float*)d_in[14];
    const float* db1i = (const float*)d_in[15];
    const float* db1h = (const float*)d_in[16];
    const float* oW   = (const float*)d_in[17];
    const float* ob   = (const float*)d_in[18];

    float* ws = (float*)d_ws;
    float* h0a = ws + OFF_H0A;
    float* h0b = ws + OFF_H0B;
    float* h1a = ws + OFF_H1A;
    float* h1b = ws + OFF_H1B;
    float* Wf  = ws + OFF_WF;
    float* bf  = ws + OFF_BF;
    unsigned* ctrs = (unsigned*)(ws + OFF_CTR);
    unsigned* clm  = (unsigned*)(ws + OFF_CLM);
    float* outf = (float*)d_out;

    // zero barrier counters + claim counters (MALL-coherent); h buffers are
    // always written-before-read in-kernel, no memset needed.
    hipMemsetAsync((void*)ctrs, 0, (2048 + 64) * sizeof(unsigned), stream);

    fuse_wb<<<dim3(768), dim3(256), 0, stream>>>(dW0i, oW, ob, db0i, Wf, bf);

    void* kargs[] = {
        (void*)&pose,
        (void*)&eW0i, (void*)&eW0h, (void*)&eb0i, (void*)&eb0h,
        (void*)&eW1i, (void*)&eW1h, (void*)&eb1i, (void*)&eb1h,
        (void*)&dW0i, (void*)&dW0h, (void*)&db0i, (void*)&db0h,
        (void*)&dW1i, (void*)&dW1h, (void*)&db1i, (void*)&db1h,
        (void*)&oW, (void*)&ob,
        (void*)&outf,
        (void*)&h0a, (void*)&h0b, (void*)&h1a, (void*)&h1b,
        (void*)&Wf, (void*)&bf,
        (void*)&ctrs, (void*)&clm
    };
    hipLaunchCooperativeKernel((const void*)behav_main, dim3(256), dim3(512),
                               kargs, 0, stream);
}

// Round 12
// 2666.866 us; speedup vs baseline: 5.7086x; 1.1988x over previous
//
#include <hip/hip_runtime.h>
#include <cstddef>
#include <cstdint>

// ---------------------------------------------------------------------------
// GRU seq2seq via MFMA. fp16 weights (single copy) x fp16 hi/lo-split acts.
// 32 clusters x 16 samples; 8 WGs/cluster (32 units each); WG = 8 waves.
// Round-12: r10-proven MALL atomic barrier (the sc0-poll flag barrier hung
// twice - r9, r11 - and is abandoned) + r11's barrier-shadow MFMA:
//   shadow1 (inside bar1 wait): p2 h-halves + proj, depend only on Ah.
//   shadow2 (inside bar2 wait): next step's p1 h-part, depends only on Bh
//   (W0h era-stable). Serial path = 2/3 W1 + 1/3 W2 + 2 hidden barriers.
// Dynamic XCD clustering via s_getreg(HW_REG_XCC_ID) claim (r10-proven);
// h exchange: plain stores -> XCD L2, sc0 staged loads (r10-proven).
// ---------------------------------------------------------------------------

typedef __attribute__((ext_vector_type(8))) _Float16 half8v;
typedef __attribute__((ext_vector_type(4))) float float4v;
typedef __attribute__((ext_vector_type(4))) unsigned uint4v;

static const size_t OFF_H0A = 0;                    // 512*256 (packed u32)
static const size_t OFF_H1A = 131072;
static const size_t OFF_H0B = 262144;
static const size_t OFF_H1B = 393216;
static const size_t OFF_WF  = 524288;               // 768*256
static const size_t OFF_BF  = OFF_WF + 196608;      // 768 (pad 1024)
static const size_t OFF_CTR = OFF_BF + 1024;        // 32*64 uints (MALL barrier)
static const size_t OFF_CLM = OFF_CTR + 2048;       // 8 uints (XCD claim), pad 64

#define SIGF(x) (1.0f / (1.0f + __expf(-(x))))
#define MFMA16F __builtin_amdgcn_mfma_f32_16x16x32_f16
#define MM2(C, W, BH, BL) \
    C = MFMA16F(W, BH, C, 0, 0, 0); \
    C = MFMA16F(W, BL, C, 0, 0, 0);

__device__ __forceinline__ unsigned pack_h(float x) {
    _Float16 h = (_Float16)x;
    _Float16 l = (_Float16)(x - (float)h);
    unsigned short uh = __builtin_bit_cast(unsigned short, h);
    unsigned short ul = __builtin_bit_cast(unsigned short, l);
    return (unsigned)uh | ((unsigned)ul << 16);
}

// 32B sc0 load: bypass L1, read the XCD-shared L2 (fresh vs other CUs).
__device__ __forceinline__ void ld32_sc0(const void* p, uint4v& a, uint4v& b) {
    asm volatile("global_load_dwordx4 %0, %2, off sc0\n\t"
                 "global_load_dwordx4 %1, %2, off offset:16 sc0\n\t"
                 "s_waitcnt vmcnt(0)"
                 : "=v"(a), "=v"(b) : "v"(p) : "memory");
}

// Wf = dec_Wih0 @ outW ; bf = dec_Wih0 @ out_b + dec_bih0
__global__ void fuse_wb(const float* __restrict__ Wih0, const float* __restrict__ oW,
                        const float* __restrict__ ob, const float* __restrict__ bih0,
                        float* __restrict__ Wf, float* __restrict__ bf) {
    int idx = blockIdx.x * 256 + threadIdx.x;
    int r = idx >> 8, h = idx & 255;
    const float* wr = Wih0 + (size_t)r * 128;
    float a = 0.f;
    for (int k = 0; k < 128; ++k) a = fmaf(wr[k], oW[(size_t)k * 256 + h], a);
    Wf[idx] = a;
    if (h == 0) {
        float b = 0.f;
        for (int k = 0; k < 128; ++k) b = fmaf(wr[k], ob[k], b);
        bf[r] = b + bih0[r];
    }
}

__global__ __launch_bounds__(512, 1)
void behav_main(
    const float* __restrict__ pose,
    const float* __restrict__ eW0i, const float* __restrict__ eW0h,
    const float* __restrict__ eb0i, const float* __restrict__ eb0h,
    const float* __restrict__ eW1i, const float* __restrict__ eW1h,
    const float* __restrict__ eb1i, const float* __restrict__ eb1h,
    const float* __restrict__ dW0i, const float* __restrict__ dW0h,
    const float* __restrict__ db0i, const float* __restrict__ db0h,
    const float* __restrict__ dW1i, const float* __restrict__ dW1h,
    const float* __restrict__ db1i, const float* __restrict__ db1h,
    const float* __restrict__ oW, const float* __restrict__ ob,
    float* __restrict__ out,
    float* h0a, float* h0b, float* h1a, float* h1b,
    const float* __restrict__ Wf, const float* __restrict__ bf,
    unsigned* ctrs, unsigned* clm)
{
    // SLOT A: h1_prev. SLOT B: h0. fp16 hi/lo, chunk-XOR swizzled.
    __shared__ _Float16 Ah[16][256], Al[16][256], Bh[16][256], Bl[16][256]; // 32 KB
    __shared__ float Gt[28 * 288];     // [slot][row 16][col 16 pad 18] 31.5 KB
    __shared__ float Hp0[16][32], Hp1[16][32];                              // 4 KB
    __shared__ unsigned s_lin;
    // Gt slots: 0-5 p1 tiles (i-part when pre, else full) | 22,23 p1 n-h
    //   24-27 p1 rz-h (shadow2) | 6-17 p2 h-halves | 18,19 proj | 4,5,20,21 W2 n-i

    const int tid = threadIdx.x;
    const int lane = tid & 63;
    const int w = tid >> 6;

    // -------- dynamic XCD-local cluster formation (r10-proven) --------
    if (tid == 0) {
        unsigned xcc;
        asm volatile("s_getreg_b32 %0, hwreg(HW_REG_XCC_ID)" : "=s"(xcc));
        xcc &= 7u;
        unsigned pos = __hip_atomic_fetch_add(&clm[xcc], 1u,
                           __ATOMIC_RELAXED, __HIP_MEMORY_SCOPE_AGENT);
        s_lin = (xcc << 5) | (pos & 31u);
    }
    __syncthreads();
    const unsigned lin = s_lin;
    const int c = (int)(lin >> 3);              // xcc*4 + grp: XCD-tied
    const int uwg = (int)(lin & 7);
    const int s0 = c << 4, j0 = uwg << 5;
    unsigned* ctr = ctrs + (c << 6);            // MALL barrier counter
    unsigned epoch = 0;

    unsigned* h0pk[2] = { (unsigned*)h0a, (unsigned*)h0b };
    unsigned* h1pk[2] = { (unsigned*)h1a, (unsigned*)h1b };
    int pp = 0;

    const float4v FZ = {0.f, 0.f, 0.f, 0.f};
    const float obv = ((tid & 31) < 16) ? ob[(uwg << 4) + (tid & 31)] : 0.f;

    // MALL atomic barrier, split arrive/wait (mechanism r10-proven).
    // arrive: syncthreads drains vmcnt -> h plain-stores L2-acked, then +1.
    auto arrive = [&]() {
        __syncthreads();
        ++epoch;
        if (tid == 0)
            __hip_atomic_fetch_add(ctr, 1u, __ATOMIC_RELAXED, __HIP_MEMORY_SCOPE_AGENT);
    };
    auto waitf = [&]() {
        if (tid == 0) {
            unsigned tgt = epoch * 8u;
            while (__hip_atomic_load(ctr, __ATOMIC_RELAXED, __HIP_MEMORY_SCOPE_AGENT) < tgt)
                __builtin_amdgcn_s_sleep(1);
        }
        __syncthreads();
    };

    // weight frag: lane holds W[row0+(lane&15)][col0+(lane>>4)*8 ..+7] as fp16
    auto ldfrag = [&](const float* M, int ldm, int row0, int col0, half8v& wv) {
        const float* p = M + (size_t)(row0 + (lane & 15)) * ldm + col0 + ((lane >> 4) << 3);
        float4 a = *(const float4*)p;
        float4 b = *(const float4*)(p + 4);
        float vv[8] = {a.x, a.y, a.z, a.w, b.x, b.y, b.z, b.w};
        #pragma unroll
        for (int i = 0; i < 8; ++i) wv[i] = (_Float16)vv[i];
    };
    auto rdS = [&](const _Float16 (*arr)[256], int kloc) -> half8v {
        int s = lane & 15, o = lane >> 4;
        int phys = ((kloc << 2) + o) ^ (s & 7);
        return *(const half8v*)&arr[s][phys << 3];
    };
    auto rdX = [&](int t, int loc, half8v& bh, half8v& bl) {
        const float* p = pose + (size_t)(s0 + (lane & 15)) * 8192 + (size_t)t * 128
                         + (loc << 5) + ((lane >> 4) << 3);
        float4 a = *(const float4*)p;
        float4 b = *(const float4*)(p + 4);
        float vv[8] = {a.x, a.y, a.z, a.w, b.x, b.y, b.z, b.w};
        #pragma unroll
        for (int i = 0; i < 8; ++i) {
            _Float16 h = (_Float16)vv[i];
            bh[i] = h;
            bl[i] = (_Float16)(vv[i] - (float)h);
        }
    };
    // stage packed h: 2 x dwordx4 sc0 loads (shared L2) -> swizzled LDS
    auto stage = [&](_Float16 (*ha)[256], _Float16 (*la)[256], const unsigned* src) {
        int s = tid >> 5, cc = tid & 31;
        uint4v a, b;
        ld32_sc0((const void*)(src + (size_t)(s0 + s) * 256 + (cc << 3)), a, b);
        unsigned u[8] = {a.x, a.y, a.z, a.w, b.x, b.y, b.z, b.w};
        half8v hv, lv;
        #pragma unroll
        for (int i = 0; i < 8; ++i) {
            hv[i] = __builtin_bit_cast(_Float16, (unsigned short)(u[i] & 0xFFFF));
            lv[i] = __builtin_bit_cast(_Float16, (unsigned short)(u[i] >> 16));
        }
        int phys = cc ^ (s & 7);
        *(half8v*)&ha[s][phys << 3] = hv;
        *(half8v*)&la[s][phys << 3] = lv;
    };
    auto gdump = [&](int slot, float4v a) {
        int col = lane & 15, ro = (lane >> 4) << 2;
        float* b = &Gt[slot * 288 + ro * 18 + col];
        b[0] = a.x; b[18] = a.y; b[36] = a.z; b[54] = a.w;
    };
    auto gtr = [&](int slot, int r16, int s) -> float {
        return Gt[slot * 288 + r16 * 18 + s];
    };

    // ---- register-stationary weights: <=28 frags/wave ----
    half8v WA[16], WB[8], WC[4];
    float b0r, b0z, b0ni, b0nh, b1r, b1z, b1ni, b1nh;

    auto load_era = [&](const float* W0i, bool x128, const float* W0h,
                        const float* W1i, const float* W1h) {
        if (w < 6) {
            const int rb1 = ((w >> 1) << 8) + j0 + ((w & 1) << 4);
            if (x128) {
                #pragma unroll
                for (int cc = 0; cc < 4; ++cc) ldfrag(W0i, 128, rb1, cc << 5, WA[cc]);
            } else {
                #pragma unroll
                for (int cc = 0; cc < 8; ++cc) ldfrag(W0i, 256, rb1, cc << 5, WA[cc]);
            }
            #pragma unroll
            for (int cc = 0; cc < 8; ++cc) ldfrag(W0h, 256, rb1, cc << 5, WA[8 + cc]);
            const int t2 = w >> 1;
            const int rb2 = ((t2 >> 1) << 8) + j0 + ((t2 & 1) << 4);
            const int kb = (w & 1) << 2;
            #pragma unroll
            for (int cc = 0; cc < 4; ++cc) ldfrag(W1h, 256, rb2, (kb + cc) << 5, WC[cc]);
            if (w < 4) {
                #pragma unroll
                for (int cc = 0; cc < 8; ++cc) ldfrag(W1i, 256, rb1, cc << 5, WB[cc]);
            } else {
                const int rb3 = 512 + j0 + ((w - 4) << 4);
                #pragma unroll
                for (int cc = 0; cc < 4; ++cc) ldfrag(W1i, 256, rb3, cc << 5, WB[cc]);
            }
        } else {
            #pragma unroll
            for (int j = 0; j < 3; ++j) {
                const int hh = 6 + (w - 6) * 3 + j;
                const int t2 = hh >> 1;
                const int rb2 = ((t2 >> 1) << 8) + j0 + ((t2 & 1) << 4);
                const int kb = (hh & 1) << 2;
                #pragma unroll
                for (int cc = 0; cc < 4; ++cc)
                    ldfrag(W1h, 256, rb2, (kb + cc) << 5, WA[4 * j + cc]);
            }
            #pragma unroll
            for (int cc = 0; cc < 4; ++cc)
                ldfrag(oW, 256, uwg << 4, (((w - 6) << 2) + cc) << 5, WA[12 + cc]);
            const int rb3 = 512 + j0 + ((w - 6) << 4);
            #pragma unroll
            for (int cc = 0; cc < 4; ++cc) ldfrag(W1i, 256, rb3, (4 + cc) << 5, WB[cc]);
        }
    };
    auto ldb0 = [&](const float* bi, const float* bhh) {
        int jj = j0 + (tid & 31);
        b0r = bi[jj] + bhh[jj]; b0z = bi[256 + jj] + bhh[256 + jj];
        b0ni = bi[512 + jj]; b0nh = bhh[512 + jj];
    };
    auto ldb1 = [&](const float* bi, const float* bhh) {
        int jj = j0 + (tid & 31);
        b1r = bi[jj] + bhh[jj]; b1z = bi[256 + jj] + bhh[256 + jj];
        b1ni = bi[512 + jj]; b1nh = bhh[512 + jj];
    };

    // ---- windows (split by dependency) ----
    // Phase A: p1 i-part (Ah or X); + h-part (Bh) only when !pre.
    auto phaseA = [&](int t, bool xs, bool pre) {
        if (w >= 6) return;
        float4v accI = FZ;
        if (xs) {
            #pragma unroll
            for (int cc = 0; cc < 4; ++cc) {
                half8v bh, bl; rdX(t, cc, bh, bl);
                MM2(accI, WA[cc], bh, bl);
            }
        } else {
            #pragma unroll
            for (int cc = 0; cc < 8; ++cc) {
                half8v bh = rdS(Ah, cc), bl = rdS(Al, cc);
                MM2(accI, WA[cc], bh, bl);
            }
        }
        if (!pre) {
            if (w < 4) {
                #pragma unroll
                for (int cc = 0; cc < 8; ++cc) {
                    half8v bh = rdS(Bh, cc), bl = rdS(Bl, cc);
                    MM2(accI, WA[8 + cc], bh, bl);
                }
                gdump(w, accI);
            } else {
                float4v accH = FZ;
                #pragma unroll
                for (int cc = 0; cc < 8; ++cc) {
                    half8v bh = rdS(Bh, cc), bl = rdS(Bl, cc);
                    MM2(accH, WA[8 + cc], bh, bl);
                }
                gdump(w, accI);
                gdump(22 + (w - 4), accH);
            }
        } else {
            gdump(w, accI);
        }
    };
    // Shadow2 (inside bar2 wait): NEXT step's p1 h-part from Bh (era-stable W0h).
    auto shadow2 = [&]() {
        if (w >= 6) return;
        float4v accH = FZ;
        #pragma unroll
        for (int cc = 0; cc < 8; ++cc) {
            half8v bh = rdS(Bh, cc), bl = rdS(Bl, cc);
            MM2(accH, WA[8 + cc], bh, bl);
        }
        gdump((w < 4) ? (24 + w) : (22 + (w - 4)), accH);
    };
    // Shadow1 (inside bar1 wait): p2 h-halves + proj from Ah (= h1_prev).
    auto shadow1 = [&](bool pj) {
        if (w < 6) {
            float4v accP = FZ;
            const int kb = (w & 1) << 2;
            #pragma unroll
            for (int cc = 0; cc < 4; ++cc) {
                half8v bh = rdS(Ah, kb + cc), bl = rdS(Al, kb + cc);
                MM2(accP, WC[cc], bh, bl);
            }
            gdump(6 + w, accP);
        } else {
            float4v A0 = FZ, A1 = FZ, A2 = FZ, AJ = FZ;
            const bool w6 = (w == 6);
            #pragma unroll
            for (int cc = 0; cc < 4; ++cc) {      // chunks 0-3, read once
                half8v bh = rdS(Ah, cc), bl = rdS(Al, cc);
                if (w6) {
                    MM2(A0, WA[cc], bh, bl);
                    MM2(A2, WA[8 + cc], bh, bl);
                    if (pj) { MM2(AJ, WA[12 + cc], bh, bl); }
                } else {
                    MM2(A1, WA[4 + cc], bh, bl);
                }
            }
            #pragma unroll
            for (int cc = 0; cc < 4; ++cc) {      // chunks 4-7, read once
                half8v bh = rdS(Ah, 4 + cc), bl = rdS(Al, 4 + cc);
                if (w6) {
                    MM2(A1, WA[4 + cc], bh, bl);
                } else {
                    MM2(A0, WA[cc], bh, bl);
                    MM2(A2, WA[8 + cc], bh, bl);
                    if (pj) { MM2(AJ, WA[12 + cc], bh, bl); }
                }
            }
            const int base = 12 + (w - 6) * 3;
            gdump(base + 0, A0);
            gdump(base + 1, A1);
            gdump(base + 2, A2);
            if (pj) gdump(18 + (w - 6), AJ);
        }
    };
    // Phase B: p2 i-part from Bh (= h0_new).
    auto phaseB = [&]() {
        if (w < 4) {
            float4v acc = FZ;
            #pragma unroll
            for (int cc = 0; cc < 8; ++cc) {
                half8v bh = rdS(Bh, cc), bl = rdS(Bl, cc);
                MM2(acc, WB[cc], bh, bl);
            }
            gdump(w, acc);
        } else {
            float4v acc = FZ;
            const int kb = (w >= 6) ? 4 : 0;
            #pragma unroll
            for (int cc = 0; cc < 4; ++cc) {
                half8v bh = rdS(Bh, kb + cc), bl = rdS(Bl, kb + cc);
                MM2(acc, WB[cc], bh, bl);
            }
            const int sl = (w == 4) ? 4 : (w == 5) ? 20 : (w == 6) ? 5 : 21;
            gdump(sl, acc);
        }
    };
    auto epi1 = [&](unsigned* pongpk, bool pre) {
        int s = tid >> 5, ul = tid & 31, t2 = ul >> 4, r16 = ul & 15;
        float gr = gtr(t2, r16, s);
        float gz = gtr(2 + t2, r16, s);
        if (pre) { gr += gtr(24 + t2, r16, s); gz += gtr(26 + t2, r16, s); }
        float r = SIGF(gr + b0r);
        float z = SIGF(gz + b0z);
        float n = tanhf(gtr(4 + t2, r16, s) + b0ni + r * (gtr(22 + t2, r16, s) + b0nh));
        float h = (1.f - z) * n + z * Hp0[s][ul];
        Hp0[s][ul] = h;
        pongpk[(size_t)(s0 + s) * 256 + j0 + ul] = pack_h(h);   // plain store -> L2
    };
    auto epi2 = [&](unsigned* pongpk) {
        int s = tid >> 5, ul = tid & 31, t2 = ul >> 4, r16 = ul & 15;
        float r = SIGF(gtr(t2, r16, s) + gtr(6 + (t2 << 1), r16, s)
                       + gtr(7 + (t2 << 1), r16, s) + b1r);
        float z = SIGF(gtr(2 + t2, r16, s) + gtr(10 + (t2 << 1), r16, s)
                       + gtr(11 + (t2 << 1), r16, s) + b1z);
        int nia = t2 ? 20 : 4, nib = t2 ? 21 : 5;
        float ni = gtr(nia, r16, s) + gtr(nib, r16, s);
        float nh = gtr(14 + (t2 << 1), r16, s) + gtr(15 + (t2 << 1), r16, s);
        float n = tanhf(ni + b1ni + r * (nh + b1nh));
        float h = (1.f - z) * n + z * Hp1[s][ul];
        Hp1[s][ul] = h;
        pongpk[(size_t)(s0 + s) * 256 + j0 + ul] = pack_h(h);   // plain store -> L2
    };
    auto epi_proj = [&](int tq) {
        int s = tid >> 5, ul = tid & 31;
        if (ul < 16) {
            float v = gtr(18, ul, s) + gtr(19, ul, s) + obv;
            out[(size_t)(s0 + s) * 65536 + (size_t)tq * 128 + (uwg << 4) + ul] = v;
        }
    };

    auto step = [&](int t, bool xs, bool pj, bool pre, bool sh2) {
        phaseA(t, xs, pre);
        __syncthreads();                    // sync1: Phase A dumps visible
        epi1(h0pk[pp ^ 1], pre);
        arrive();                           // bar1 arrive (h0_new L2-acked)
        shadow1(pj);                        //   Ah-dependent work in wait shadow
        waitf();                            // bar1 done (+ shadow1 dumps visible)
        stage(Bh, Bl, h0pk[pp ^ 1]);
        if (pj) epi_proj(t - 1);
        __syncthreads();                    // sync2: slot B = h0_new ready
        phaseB();
        __syncthreads();                    // sync3: Phase B dumps visible
        epi2(h1pk[pp ^ 1]);
        arrive();                           // bar2 arrive (h1_new L2-acked)
        if (sh2) shadow2();                 //   next-step Bh-dependent work
        waitf();                            // bar2 done
        stage(Ah, Al, h1pk[pp ^ 1]);
        __syncthreads();                    // sync4: slot A = h1_new ready
        pp ^= 1;
    };

    // ---- init ----
    {
        int s = tid >> 5, cc = tid & 31;
        half8v z;
        #pragma unroll
        for (int i = 0; i < 8; ++i) z[i] = (_Float16)0.f;
        *(half8v*)&Ah[s][cc << 3] = z;
        *(half8v*)&Al[s][cc << 3] = z;
        *(half8v*)&Bh[s][cc << 3] = z;
        *(half8v*)&Bl[s][cc << 3] = z;
        Hp0[s][cc] = 0.f;
        Hp1[s][cc] = 0.f;
    }
    __syncthreads();

    // ===================== ENCODER =====================
    load_era(eW0i, true, eW0h, eW1i, eW1h);
    ldb0(eb0i, eb0h); ldb1(eb1i, eb1h);
    for (int t = 0; t < 64; ++t) step(t, true, false, t > 0, t < 63);

    // ===================== DECODER =====================
    load_era(dW0i, true, dW0h, dW1i, dW1h);
    ldb0(db0i, db0h); ldb1(db1i, db1h);
    for (int t = 0; t < 512; ++t) {
        if (t == 64) {                      // AR era: only W0i-side changes
            if (w < 6) {
                const int rb1 = ((w >> 1) << 8) + j0 + ((w & 1) << 4);
                #pragma unroll
                for (int cc = 0; cc < 8; ++cc) ldfrag(Wf, 256, rb1, cc << 5, WA[cc]);
            }
            int jj = j0 + (tid & 31);
            b0r = bf[jj] + db0h[jj];
            b0z = bf[256 + jj] + db0h[256 + jj];
            b0ni = bf[512 + jj];
            b0nh = db0h[512 + jj];
        }
        step(t, t < 64, t >= 1, t > 0, t < 511);
    }

    // ===================== tail: out[511] = proj(h1_511) =====================
    if (w >= 6) {
        float4v accJ = FZ;
        const int cb = (w - 6) << 2;
        #pragma unroll
        for (int cc = 0; cc < 4; ++cc) {
            half8v bh = rdS(Ah, cb + cc), bl = rdS(Al, cb + cc);
            MM2(accJ, WA[12 + cc], bh, bl);
        }
        gdump(18 + (w - 6), accJ);
    }
    __syncthreads();
    epi_proj(511);
}

extern "C" void kernel_launch(void* const* d_in, const int* in_sizes, int n_in,
                              void* d_out, int out_size, void* d_ws, size_t ws_size,
                              hipStream_t stream) {
    (void)in_sizes; (void)n_in; (void)out_size; (void)ws_size;

    const float* pose = (const float*)d_in[0];
    const float* eW0i = (const float*)d_in[1];
    const float* eW0h = (const float*)d_in[2];
    const float* eb0i = (const float*)d_in[3];
    const float* eb0h = (const float*)d_in[4];
    const float* eW1i = (const float*)d_in[5];
    const float* eW1h = (const float*)d_in[6];
    const float* eb1i = (const float*)d_in[7];
    const float* eb1h = (const float*)d_in[8];
    const float* dW0i = (const float*)d_in[9];
    const float* dW0h = (const float*)d_in[10];
    const float* db0i = (const float*)d_in[11];
    const float* db0h = (const float*)d_in[12];
    const float* dW1i = (const float*)d_in[13];
    const float* dW1h = (const float*)d_in[14];
    const float* db1i = (const float*)d_in[15];
    const float* db1h = (const float*)d_in[16];
    const float* oW   = (const float*)d_in[17];
    const float* ob   = (const float*)d_in[18];

    float* ws = (float*)d_ws;
    float* h0a = ws + OFF_H0A;
    float* h0b = ws + OFF_H0B;
    float* h1a = ws + OFF_H1A;
    float* h1b = ws + OFF_H1B;
    float* Wf  = ws + OFF_WF;
    float* bf  = ws + OFF_BF;
    unsigned* ctrs = (unsigned*)(ws + OFF_CTR);
    unsigned* clm  = (unsigned*)(ws + OFF_CLM);
    float* outf = (float*)d_out;

    // zero MALL barrier counters + XCD claim counters (replayed in graph).
    hipMemsetAsync((void*)ctrs, 0, (2048 + 64) * sizeof(unsigned), stream);

    fuse_wb<<<dim3(768), dim3(256), 0, stream>>>(dW0i, oW, ob, db0i, Wf, bf);

    void* kargs[] = {
        (void*)&pose,
        (void*)&eW0i, (void*)&eW0h, (void*)&eb0i, (void*)&eb0h,
        (void*)&eW1i, (void*)&eW1h, (void*)&eb1i, (void*)&eb1h,
        (void*)&dW0i, (void*)&dW0h, (void*)&db0i, (void*)&db0h,
        (void*)&dW1i, (void*)&dW1h, (void*)&db1i, (void*)&db1h,
        (void*)&oW, (void*)&ob,
        (void*)&outf,
        (void*)&h0a, (void*)&h0b, (void*)&h1a, (void*)&h1b,
        (void*)&Wf, (void*)&bf,
        (void*)&ctrs, (void*)&clm
    };
    hipLaunchCooperativeKernel((const void*)behav_main, dim3(256), dim3(512),
                               kargs, 0, stream);
}